// Round 12
// baseline (260.412 us; speedup 1.0000x reference)
//
#include <hip/hip_runtime.h>
#include <hip/hip_bf16.h>

#define NN 50000      // nodes
#define MP 50176      // padded nodes (392 * 128)
#define NF 64         // features
#define NH 512        // hidden
#define NE 800000     // edges
#define NB 196        // scan blocks = ceil(NN/256)
#define MB 392        // M blocks = MP/128
#define GRID (MB * 4) // 1568 = 8 * 196
#define CPX (GRID / 8)

typedef __attribute__((ext_vector_type(8))) short bf16x8;
typedef __attribute__((ext_vector_type(4))) float f32x4;

#define GLOAD16(g, l)                                                        \
    __builtin_amdgcn_global_load_lds(                                        \
        (const __attribute__((address_space(1))) unsigned int*)(g),          \
        (__attribute__((address_space(3))) unsigned int*)(l), 16, 0, 0)

// ---------------------------------------------------------------------------
// detect whether edge_index is int64 (high dwords all zero) or int32
__global__ void detect_idx(const int* __restrict__ ei, int* __restrict__ flag) {
    if (threadIdx.x == 0 && blockIdx.x == 0) {
        int any = 0;
        for (int i = 0; i < 32; ++i) any |= ei[2 * i + 1];
        *flag = (any == 0) ? 1 : 0;   // 1 => int64 layout
    }
}

// ---------------------------------------------------------------------------
// CSR build: histogram of dst
__global__ __launch_bounds__(256) void edge_hist(const void* __restrict__ eiv,
                                                 const int* __restrict__ flag,
                                                 int* __restrict__ deg) {
    int e = blockIdx.x * 256 + threadIdx.x;
    if (e >= NE) return;
    int dst = *flag ? (int)((const long long*)eiv)[NE + e]
                    : ((const int*)eiv)[NE + e];
    atomicAdd(&deg[dst], 1);
}

// parallel scan step 1: per-block exclusive prefix + block sums
__global__ __launch_bounds__(256) void scan_local(const int* __restrict__ deg,
                                                  int* __restrict__ rowptr,
                                                  int* __restrict__ bsum) {
    __shared__ int sm[256];
    int tid = threadIdx.x;
    int i = blockIdx.x * 256 + tid;
    int v = (i < NN) ? deg[i] : 0;
    sm[tid] = v;
    __syncthreads();
    int acc = v;
#pragma unroll
    for (int off = 1; off < 256; off <<= 1) {
        int t = (tid >= off) ? sm[tid - off] : 0;
        __syncthreads();
        acc += t;
        sm[tid] = acc;
        __syncthreads();
    }
    if (i < NN) rowptr[i] = acc - v;           // local exclusive
    if (tid == 255) bsum[blockIdx.x] = acc;    // block total
}

// parallel scan step 2: exclusive scan of the NB block sums (1 block)
__global__ __launch_bounds__(256) void scan_bsum(const int* __restrict__ bsum,
                                                 int* __restrict__ boff) {
    __shared__ int sm[256];
    int tid = threadIdx.x;
    int v = (tid < NB) ? bsum[tid] : 0;
    sm[tid] = v;
    __syncthreads();
    int acc = v;
#pragma unroll
    for (int off = 1; off < 256; off <<= 1) {
        int t = (tid >= off) ? sm[tid - off] : 0;
        __syncthreads();
        acc += t;
        sm[tid] = acc;
        __syncthreads();
    }
    if (tid < NB) boff[tid] = acc - v;         // exclusive
}

// parallel scan step 3: add block offsets, emit rowptr & cursor
__global__ __launch_bounds__(256) void scan_add(int* __restrict__ rowptr,
                                                const int* __restrict__ boff,
                                                int* __restrict__ cursor) {
    int i = blockIdx.x * 256 + threadIdx.x;
    if (i < NN) {
        int r = rowptr[i] + boff[blockIdx.x];
        rowptr[i] = r;
        cursor[i] = r;
    }
    if (i == 0) rowptr[NN] = NE;   // total is the edge count by construction
}

// scatter edge sources into CSR slots. NOTE: atomicExch, not a plain store —
// scattered 4B stores dirty a full 64B line each (R11: 53 MB write-back for
// 3.2 MB of data); atomics write through at 4B granularity (R2 evidence).
__global__ __launch_bounds__(256) void edge_fill(const void* __restrict__ eiv,
                                                 const int* __restrict__ flag,
                                                 int* __restrict__ cursor,
                                                 int* __restrict__ csr) {
    int e = blockIdx.x * 256 + threadIdx.x;
    if (e >= NE) return;
    int src, dst;
    if (*flag) {
        const long long* ei = (const long long*)eiv;
        src = (int)ei[e];
        dst = (int)ei[NE + e];
    } else {
        const int* ei = (const int*)eiv;
        src = ei[e];
        dst = ei[NE + e];
    }
    int pos = atomicAdd(&cursor[dst], 1);
    atomicExch(&csr[pos], src);
}

// x fp32 -> bf16 (halves gather's L3-resident re-read stream)
__global__ __launch_bounds__(256) void cvt_x(const float* __restrict__ x,
                                             __hip_bfloat16* __restrict__ xb) {
    int t = blockIdx.x * 256 + threadIdx.x;
    if (t >= NN * NF / 4) return;
    float4 v = *(const float4*)&x[t * 4];
    union { ushort4 u; __hip_bfloat16 h[4]; } o;
    o.h[0] = __float2bfloat16(v.x);
    o.h[1] = __float2bfloat16(v.y);
    o.h[2] = __float2bfloat16(v.z);
    o.h[3] = __float2bfloat16(v.w);
    *(ushort4*)&xb[t * 4] = o.u;
}

// gather-sum, one WAVE per node (lane = feature), bf16 x rows, fp32 accum.
__global__ __launch_bounds__(256) void gather(const __hip_bfloat16* __restrict__ xb,
                                              const int* __restrict__ rowptr,
                                              const int* __restrict__ csr,
                                              __hip_bfloat16* __restrict__ h0b) {
    int n = blockIdx.x * 4 + (threadIdx.x >> 6);   // node id
    int lane = threadIdx.x & 63;
    if (n >= MP) return;
    if (n >= NN) {
        h0b[(long long)n * NF + lane] = __float2bfloat16(0.f);
        return;
    }
    float acc = __bfloat162float(xb[(long long)n * NF + lane]);
    int e = rowptr[n], e1 = rowptr[n + 1];
    for (; e + 4 <= e1; e += 4) {
        int s0 = csr[e], s1 = csr[e + 1], s2 = csr[e + 2], s3 = csr[e + 3];
        float v0 = __bfloat162float(xb[(long long)s0 * NF + lane]);
        float v1 = __bfloat162float(xb[(long long)s1 * NF + lane]);
        float v2 = __bfloat162float(xb[(long long)s2 * NF + lane]);
        float v3 = __bfloat162float(xb[(long long)s3 * NF + lane]);
        acc += (v0 + v1) + (v2 + v3);
    }
    for (; e < e1; ++e) acc += __bfloat162float(xb[(long long)csr[e] * NF + lane]);
    h0b[(long long)n * NF + lane] = __float2bfloat16(acc);
}

// W [K][N] fp32 -> WT [N][K] bf16
__global__ __launch_bounds__(256) void cvt_wt(const float* __restrict__ W,
                                              __hip_bfloat16* __restrict__ WT,
                                              int K, int N) {
    int t = blockIdx.x * 256 + threadIdx.x;
    if (t >= K * N) return;
    int n = t % N, k = t / N;
    WT[n * K + k] = __float2bfloat16(W[t]);
}

// ---------------------------------------------------------------------------
// GEMM1 (K=64): fully direct — A and B fragments read straight from global.
__global__ __launch_bounds__(256) void gemm1_direct(const __hip_bfloat16* __restrict__ A,
                                                    const __hip_bfloat16* __restrict__ BT,
                                                    const float* __restrict__ bias,
                                                    __hip_bfloat16* __restrict__ C) {
    const int orig = blockIdx.x;
    const int L = (orig & 7) * CPX + (orig >> 3);
    const int mb = L >> 2, nb = L & 3;

    const int tid = threadIdx.x;
    const int lane = tid & 63;
    const int w = tid >> 6;
    const int wm = w >> 1, wn = w & 1;
    const long long rbase = (long long)mb * 128;
    const int nbase = nb * 128;
    const int lo = lane & 15, hi = lane >> 4;

    f32x4 acc[4][4];
#pragma unroll
    for (int i = 0; i < 4; ++i)
#pragma unroll
        for (int j = 0; j < 4; ++j) acc[i][j] = (f32x4){0.f, 0.f, 0.f, 0.f};

#pragma unroll
    for (int ks = 0; ks < 2; ++ks) {
        bf16x8 af[4], bfr[4];
#pragma unroll
        for (int mi = 0; mi < 4; ++mi)
            af[mi] = *(const bf16x8*)&A[(rbase + wm * 64 + mi * 16 + lo) * NF +
                                        ks * 32 + hi * 8];
#pragma unroll
        for (int ni = 0; ni < 4; ++ni)
            bfr[ni] = *(const bf16x8*)&BT[(long long)(nbase + wn * 64 + ni * 16 + lo) * NF +
                                          ks * 32 + hi * 8];
#pragma unroll
        for (int mi = 0; mi < 4; ++mi)
#pragma unroll
            for (int ni = 0; ni < 4; ++ni)
                acc[mi][ni] = __builtin_amdgcn_mfma_f32_16x16x32_bf16(
                    af[mi], bfr[ni], acc[mi][ni], 0, 0, 0);
    }

    const int col0 = nbase + wn * 64 + lo;
    const long long row00 = rbase + wm * 64 + hi * 4;
#pragma unroll
    for (int ni = 0; ni < 4; ++ni) {
        int col = col0 + ni * 16;
        float bv = bias[col];
#pragma unroll
        for (int mi = 0; mi < 4; ++mi) {
            long long r0 = row00 + mi * 16;
#pragma unroll
            for (int r = 0; r < 4; ++r) {
                float v = fmaxf(acc[mi][ni][r] + bv, 0.f);   // ReLU
                C[(r0 + r) * NH + col] = __float2bfloat16(v);
            }
        }
    }
}

// ---------------------------------------------------------------------------
// GEMM2 (K=512): counted-vmcnt 2-deep pipeline (T3/T4 minimum form).
// Two full LDS buffer sets (A 16KB + B 16KB each, 64 KB total), both operands
// staged via global_load_lds with XOR-swizzle. Raw s_barrier + asm
// s_waitcnt vmcnt(8); NO __syncthreads in the loop.
__global__ __launch_bounds__(256) void gemm2_db(const __hip_bfloat16* __restrict__ A,
                                                const __hip_bfloat16* __restrict__ BT,
                                                const float* __restrict__ bias,
                                                __hip_bfloat16* __restrict__ C,
                                                float* __restrict__ partial) {
    constexpr int BK = 64;
    __shared__ __align__(16) char smem[65536];   // 2 sets x (A 16KB | B 16KB)
    float* smsum = (float*)smem;                 // alias set0 (dead after loop)
    float* smsq  = (float*)(smem + 2048);

    const int orig = blockIdx.x;
    const int L = (orig & 7) * CPX + (orig >> 3);
    const int mb = L >> 2, nb = L & 3;

    const int tid = threadIdx.x;
    const int lane = tid & 63;
    const int w = tid >> 6;
    const int wm = w >> 1, wn = w & 1;
    const long long rbase = (long long)mb * 128;
    const int nbase = nb * 128;
    const int r8  = lane >> 3;            // stage row within 8-row group
    const int swc = (lane & 7) ^ r8;      // pre-swizzled global chunk (rule #21)
    const int key = lane & 7;             // read-side swizzle key
    const int lo = lane & 15, hi = lane >> 4;

    const __hip_bfloat16* gaBase =
        A + (rbase + w * 32 + r8) * (long long)NH + swc * 8;
    const __hip_bfloat16* gbBase =
        BT + (long long)(nbase + w * 32 + r8) * NH + swc * 8;
    const int laOff = (w * 32) * BK;

    auto STAGE = [&](int s, int kb) {
        __hip_bfloat16* la = (__hip_bfloat16*)(smem + s * 32768) + laOff;
        __hip_bfloat16* lb = (__hip_bfloat16*)(smem + s * 32768 + 16384) + laOff;
#pragma unroll
        for (int t = 0; t < 4; ++t)
            GLOAD16(gaBase + kb + (long long)t * 8 * NH, la + t * 8 * BK);
#pragma unroll
        for (int t = 0; t < 4; ++t)
            GLOAD16(gbBase + kb + (long long)t * 8 * NH, lb + t * 8 * BK);
    };

    f32x4 acc[4][4];
#pragma unroll
    for (int i = 0; i < 4; ++i)
#pragma unroll
        for (int j = 0; j < 4; ++j) acc[i][j] = (f32x4){0.f, 0.f, 0.f, 0.f};

    // prologue: 2-deep prefetch (16 loads outstanding per wave)
    STAGE(0, 0);
    STAGE(1, BK);

#pragma unroll
    for (int t = 0; t < 8; ++t) {
        if (t == 7) { asm volatile("s_waitcnt vmcnt(0)" ::: "memory"); }
        else        { asm volatile("s_waitcnt vmcnt(8)" ::: "memory"); }
        __builtin_amdgcn_s_barrier();          // all waves' DMA for cur landed
        __builtin_amdgcn_sched_barrier(0);

        const __hip_bfloat16* Ac = (const __hip_bfloat16*)(smem + (t & 1) * 32768);
        const __hip_bfloat16* Bc = Ac + 8192;  // +16384 bytes
#pragma unroll
        for (int ks = 0; ks < 2; ++ks) {
            bf16x8 af[4], bfr[4];
#pragma unroll
            for (int mi = 0; mi < 4; ++mi)
                af[mi] = *(const bf16x8*)&Ac[(wm * 64 + mi * 16 + lo) * BK +
                                             (((ks * 4 + hi) ^ key) * 8)];
#pragma unroll
            for (int ni = 0; ni < 4; ++ni)
                bfr[ni] = *(const bf16x8*)&Bc[(wn * 64 + ni * 16 + lo) * BK +
                                              (((ks * 4 + hi) ^ key) * 8)];
#pragma unroll
            for (int mi = 0; mi < 4; ++mi)
#pragma unroll
                for (int ni = 0; ni < 4; ++ni)
                    acc[mi][ni] = __builtin_amdgcn_mfma_f32_16x16x32_bf16(
                        af[mi], bfr[ni], acc[mi][ni], 0, 0, 0);
        }
        __builtin_amdgcn_sched_barrier(0);
        __builtin_amdgcn_s_barrier();          // all waves done reading cur
        __builtin_amdgcn_sched_barrier(0);
        if (t < 6) STAGE(t & 1, (t + 2) * BK); // refill freed buffer, 2 ahead
    }

    // epilogue: vmcnt==0 here; full barrier before LDS alias reuse
    __syncthreads();
    if (tid < 128) { smsum[tid] = 0.f; smsq[tid] = 0.f; }
    __syncthreads();
    const int col0 = nbase + wn * 64 + lo;
    const long long row00 = rbase + wm * 64 + hi * 4;
#pragma unroll
    for (int ni = 0; ni < 4; ++ni) {
        int col = col0 + ni * 16;
        float bv = bias[col];
        float s = 0.f, q = 0.f;
#pragma unroll
        for (int mi = 0; mi < 4; ++mi) {
            long long r0 = row00 + mi * 16;
#pragma unroll
            for (int r = 0; r < 4; ++r) {
                float v = acc[mi][ni][r] + bv;
                C[(r0 + r) * NH + col] = __float2bfloat16(v);
                if ((r0 + r) < NN) { s += v; q += v * v; }
            }
        }
        s += __shfl_xor(s, 16); s += __shfl_xor(s, 32);
        q += __shfl_xor(q, 16); q += __shfl_xor(q, 32);
        if (lane < 16) {
            atomicAdd(&smsum[wn * 64 + ni * 16 + lane], s);
            atomicAdd(&smsq[wn * 64 + ni * 16 + lane], q);
        }
    }
    __syncthreads();
    if (tid < 128) {
        partial[mb * 1024 + nbase + tid] = smsum[tid];
        partial[mb * 1024 + 512 + nbase + tid] = smsq[tid];
    }
}

// reduce per-block partials: stats[j] = sum_mb partial[mb*1024 + j], j<1024
__global__ __launch_bounds__(256) void stats_reduce(const float* __restrict__ partial,
                                                    float* __restrict__ stats) {
    int j = blockIdx.x * 256 + threadIdx.x;   // 0..1023
    float s = 0.f;
    for (int mb = 0; mb < MB; ++mb) s += partial[mb * 1024 + j];
    stats[j] = s;
}

// BN(train stats) + ReLU + classifier fused; bf16 h2, per-lane register params
__global__ __launch_bounds__(256) void bn_cls(const __hip_bfloat16* __restrict__ h2b,
                                              const float* __restrict__ stats,
                                              const float* __restrict__ gamma,
                                              const float* __restrict__ beta,
                                              const float* __restrict__ Wc,
                                              const float* __restrict__ bc,
                                              float* __restrict__ out) {
    int tid = threadIdx.x;
    int lane = tid & 63;
    int k0 = lane * 8;
    float sc[8], sh[8], w0[8], w1[8];
#pragma unroll
    for (int j = 0; j < 8; ++j) {
        int k = k0 + j;
        float mean = stats[k] * (1.0f / NN);
        float var = stats[512 + k] * (1.0f / NN) - mean * mean;
        float rs = rsqrtf(var + 1e-5f);
        float s = gamma[k] * rs;
        sc[j] = s;
        sh[j] = beta[k] - mean * s;
        w0[j] = Wc[2 * k];
        w1[j] = Wc[2 * k + 1];
    }
    float bc0 = bc[0], bc1 = bc[1];
    int wid = blockIdx.x * 4 + (tid >> 6);
    int nw = gridDim.x * 4;
    for (int row = wid; row < NN; row += nw) {
        bf16x8 v8 = *(const bf16x8*)&h2b[(long long)row * NH + k0];
        float a0 = 0.f, a1 = 0.f;
#pragma unroll
        for (int j = 0; j < 8; ++j) {
            float v = __bfloat162float(((const __hip_bfloat16*)&v8)[j]);
            float hn = fmaxf(fmaf(v, sc[j], sh[j]), 0.f);
            a0 = fmaf(hn, w0[j], a0);
            a1 = fmaf(hn, w1[j], a1);
        }
#pragma unroll
        for (int off = 32; off; off >>= 1) {
            a0 += __shfl_xor(a0, off);
            a1 += __shfl_xor(a1, off);
        }
        if (lane == 0) {
            out[(long long)row * 2 + 0] = a0 + bc0;
            out[(long long)row * 2 + 1] = a1 + bc1;
        }
    }
}

// ---------------------------------------------------------------------------
extern "C" void kernel_launch(void* const* d_in, const int* in_sizes, int n_in,
                              void* d_out, int out_size, void* d_ws, size_t ws_size,
                              hipStream_t stream) {
    const float* x     = (const float*)d_in[0];
    const void*  ei    = d_in[1];
    const float* W1    = (const float*)d_in[2];
    const float* b1    = (const float*)d_in[3];
    const float* W2    = (const float*)d_in[4];
    const float* b2    = (const float*)d_in[5];
    const float* gamma = (const float*)d_in[6];
    const float* beta  = (const float*)d_in[7];
    const float* Wc    = (const float*)d_in[8];
    const float* bc    = (const float*)d_in[9];
    float* out = (float*)d_out;

    // workspace carve-up (256B aligned)
    char* base = (char*)d_ws;
    size_t o = 0;
    auto alloc = [&](size_t bytes) {
        char* p = base + o;
        o = (o + bytes + 255) & ~(size_t)255;
        return p;
    };
    __hip_bfloat16* h0b     = (__hip_bfloat16*)alloc((size_t)MP * NF * 2);
    __hip_bfloat16* h1b     = (__hip_bfloat16*)alloc((size_t)MP * NH * 2);
    __hip_bfloat16* h2b     = (__hip_bfloat16*)alloc((size_t)MP * NH * 2);
    __hip_bfloat16* xb      = (__hip_bfloat16*)alloc((size_t)NN * NF * 2);
    __hip_bfloat16* w1t     = (__hip_bfloat16*)alloc((size_t)NH * NF * 2);
    __hip_bfloat16* w2t     = (__hip_bfloat16*)alloc((size_t)NH * NH * 2);
    int*            deg     = (int*)alloc((size_t)NN * 4);
    int*            rowptr  = (int*)alloc((size_t)(NN + 1) * 4);
    int*            cursor  = (int*)alloc((size_t)NN * 4);
    int*            csr     = (int*)alloc((size_t)NE * 4);
    int*            bsum    = (int*)alloc((size_t)NB * 4);
    int*            boff    = (int*)alloc((size_t)NB * 4);
    float*          partial = (float*)alloc((size_t)MB * 1024 * 4);
    float*          stats   = (float*)alloc(1024 * 4);
    int*            flag    = (int*)alloc(256);

    hipMemsetAsync(deg, 0, (size_t)NN * 4, stream);
    detect_idx<<<1, 1, 0, stream>>>((const int*)ei, flag);

    // CSR build + gather
    edge_hist<<<(NE + 255) / 256, 256, 0, stream>>>(ei, flag, deg);
    scan_local<<<NB, 256, 0, stream>>>(deg, rowptr, bsum);
    scan_bsum<<<1, 256, 0, stream>>>(bsum, boff);
    scan_add<<<NB, 256, 0, stream>>>(rowptr, boff, cursor);
    edge_fill<<<(NE + 255) / 256, 256, 0, stream>>>(ei, flag, cursor, csr);
    cvt_x<<<(NN * NF / 4 + 255) / 256, 256, 0, stream>>>(x, xb);
    gather<<<MP / 4, 256, 0, stream>>>(xb, rowptr, csr, h0b);

    cvt_wt<<<(NF * NH + 255) / 256, 256, 0, stream>>>(W1, w1t, NF, NH);
    cvt_wt<<<(NH * NH + 255) / 256, 256, 0, stream>>>(W2, w2t, NH, NH);

    gemm1_direct<<<GRID, 256, 0, stream>>>(h0b, w1t, b1, h1b);
    gemm2_db<<<GRID, 256, 0, stream>>>(h1b, w2t, b2, h2b, partial);

    stats_reduce<<<4, 256, 0, stream>>>(partial, stats);
    bn_cls<<<512, 256, 0, stream>>>(h2b, stats, gamma, beta, Wc, bc, out);
}

// Round 13
// 179.755 us; speedup vs baseline: 1.4487x; 1.4487x over previous
//
#include <hip/hip_runtime.h>
#include <hip/hip_bf16.h>

#define NN 50000      // nodes
#define MP 50176      // padded nodes (392 * 128)
#define NF 64         // features
#define NH 512        // hidden
#define NE 800000     // edges
#define NBK 196       // dst buckets (dst >> 8), = scan width
#define EBCAP 8192    // per-bucket capacity (2x Poisson mean 4082, sd 64)
#define ABLK 391      // bucketA blocks (x 2048 edges)
#define MB 392        // M blocks = MP/128
#define GRID (MB * 4) // 1568 = 8 * 196
#define CPX (GRID / 8)

typedef __attribute__((ext_vector_type(8))) short bf16x8;
typedef __attribute__((ext_vector_type(4))) float f32x4;

#define GLOAD16(g, l)                                                        \
    __builtin_amdgcn_global_load_lds(                                        \
        (const __attribute__((address_space(1))) unsigned int*)(g),          \
        (__attribute__((address_space(3))) unsigned int*)(l), 16, 0, 0)

// ---------------------------------------------------------------------------
// detect whether edge_index is int64 (high dwords all zero) or int32
__global__ void detect_idx(const int* __restrict__ ei, int* __restrict__ flag) {
    if (threadIdx.x == 0 && blockIdx.x == 0) {
        int any = 0;
        for (int i = 0; i < 32; ++i) any |= ei[2 * i + 1];
        *flag = (any == 0) ? 1 : 0;   // 1 => int64 layout
    }
}

// ---------------------------------------------------------------------------
// Bucket sort pass A: partition edges into 196 dst-buckets (dst>>8).
// Scattered global atomics replaced by: LDS histogram + 196 reservation
// atomics per block + near-coalesced run writes into reserved slots.
__global__ __launch_bounds__(256) void bucketA(const void* __restrict__ eiv,
                                               const int* __restrict__ flag,
                                               int* __restrict__ bcnt,
                                               int* __restrict__ ebS,
                                               int* __restrict__ ebD) {
    __shared__ int hist[NBK];
    __shared__ int lcur[NBK];
    const int tid = threadIdx.x;
    const int chunk = blockIdx.x * 2048;
    const int lim = min(2048, NE - chunk);
    const bool is64 = (*flag != 0);
    const long long* ei64 = (const long long*)eiv;
    const int* ei32 = (const int*)eiv;

    for (int i = tid; i < NBK; i += 256) hist[i] = 0;
    __syncthreads();
    for (int i = tid; i < lim; i += 256) {
        int d = is64 ? (int)ei64[NE + chunk + i] : ei32[NE + chunk + i];
        atomicAdd(&hist[d >> 8], 1);
    }
    __syncthreads();
    for (int i = tid; i < NBK; i += 256) {
        int c = hist[i];
        lcur[i] = c ? atomicAdd(&bcnt[i], c) : 0;   // reserve run in bucket i
    }
    __syncthreads();
    for (int i = tid; i < lim; i += 256) {
        int s, d;
        if (is64) { s = (int)ei64[chunk + i]; d = (int)ei64[NE + chunk + i]; }
        else      { s = ei32[chunk + i];      d = ei32[NE + chunk + i]; }
        int b = d >> 8;
        int p = atomicAdd(&lcur[b], 1);             // LDS cursor -> global slot
        ebS[b * EBCAP + p] = s;
        ebD[b * EBCAP + p] = d;
    }
}

// exclusive scan of the NBK bucket counts (1 block) -> bucket bases
__global__ __launch_bounds__(256) void scan_bsum(const int* __restrict__ bsum,
                                                 int* __restrict__ boff) {
    __shared__ int sm[256];
    int tid = threadIdx.x;
    int v = (tid < NBK) ? bsum[tid] : 0;
    sm[tid] = v;
    __syncthreads();
    int acc = v;
#pragma unroll
    for (int off = 1; off < 256; off <<= 1) {
        int t = (tid >= off) ? sm[tid - off] : 0;
        __syncthreads();
        acc += t;
        sm[tid] = acc;
        __syncthreads();
    }
    if (tid < NBK) boff[tid] = acc - v;         // exclusive
}

// Bucket sort pass B: one block per bucket. LDS counting sort over the
// bucket's 256 nodes; writes rowptr coalesced and csr dst-sorted into
// block-owned lines (clean ~3.2 MB writeback, no global atomics).
__global__ __launch_bounds__(256) void bucketB(const int* __restrict__ ebS,
                                               const int* __restrict__ ebD,
                                               const int* __restrict__ bcnt,
                                               const int* __restrict__ bbase,
                                               int* __restrict__ rowptr,
                                               int* __restrict__ csr) {
    __shared__ int hist[256], sm[256], curs[256];
    const int b = blockIdx.x;
    const int tid = threadIdx.x;
    const int n0 = b << 8;
    const int cnt = bcnt[b];
    const int base = bbase[b];

    hist[tid] = 0;
    __syncthreads();
    for (int i = tid; i < cnt; i += 256)
        atomicAdd(&hist[ebD[b * EBCAP + i] & 255], 1);
    __syncthreads();
    int v = hist[tid];
    sm[tid] = v;
    __syncthreads();
    int acc = v;
#pragma unroll
    for (int off = 1; off < 256; off <<= 1) {
        int t = (tid >= off) ? sm[tid - off] : 0;
        __syncthreads();
        acc += t;
        sm[tid] = acc;
        __syncthreads();
    }
    int excl = acc - v;
    if (n0 + tid < NN) rowptr[n0 + tid] = base + excl;   // coalesced
    curs[tid] = excl;
    __syncthreads();
    for (int i = tid; i < cnt; i += 256) {
        int s = ebS[b * EBCAP + i];
        int d = ebD[b * EBCAP + i] & 255;
        int lp = atomicAdd(&curs[d], 1);                 // LDS cursor
        csr[base + lp] = s;
    }
    if (b == 0 && tid == 0) rowptr[NN] = NE;
}

// x fp32 -> bf16 (halves gather's L3-resident re-read stream)
__global__ __launch_bounds__(256) void cvt_x(const float* __restrict__ x,
                                             __hip_bfloat16* __restrict__ xb) {
    int t = blockIdx.x * 256 + threadIdx.x;
    if (t >= NN * NF / 4) return;
    float4 v = *(const float4*)&x[t * 4];
    union { ushort4 u; __hip_bfloat16 h[4]; } o;
    o.h[0] = __float2bfloat16(v.x);
    o.h[1] = __float2bfloat16(v.y);
    o.h[2] = __float2bfloat16(v.z);
    o.h[3] = __float2bfloat16(v.w);
    *(ushort4*)&xb[t * 4] = o.u;
}

// gather-sum, one WAVE per node (lane = feature), bf16 x rows, fp32 accum.
__global__ __launch_bounds__(256) void gather(const __hip_bfloat16* __restrict__ xb,
                                              const int* __restrict__ rowptr,
                                              const int* __restrict__ csr,
                                              __hip_bfloat16* __restrict__ h0b) {
    int n = blockIdx.x * 4 + (threadIdx.x >> 6);   // node id
    int lane = threadIdx.x & 63;
    if (n >= MP) return;
    if (n >= NN) {
        h0b[(long long)n * NF + lane] = __float2bfloat16(0.f);
        return;
    }
    float acc = __bfloat162float(xb[(long long)n * NF + lane]);
    int e = rowptr[n], e1 = rowptr[n + 1];
    for (; e + 4 <= e1; e += 4) {
        int s0 = csr[e], s1 = csr[e + 1], s2 = csr[e + 2], s3 = csr[e + 3];
        float v0 = __bfloat162float(xb[(long long)s0 * NF + lane]);
        float v1 = __bfloat162float(xb[(long long)s1 * NF + lane]);
        float v2 = __bfloat162float(xb[(long long)s2 * NF + lane]);
        float v3 = __bfloat162float(xb[(long long)s3 * NF + lane]);
        acc += (v0 + v1) + (v2 + v3);
    }
    for (; e < e1; ++e) acc += __bfloat162float(xb[(long long)csr[e] * NF + lane]);
    h0b[(long long)n * NF + lane] = __float2bfloat16(acc);
}

// W [K][N] fp32 -> WT [N][K] bf16
__global__ __launch_bounds__(256) void cvt_wt(const float* __restrict__ W,
                                              __hip_bfloat16* __restrict__ WT,
                                              int K, int N) {
    int t = blockIdx.x * 256 + threadIdx.x;
    if (t >= K * N) return;
    int n = t % N, k = t / N;
    WT[n * K + k] = __float2bfloat16(W[t]);
}

// ---------------------------------------------------------------------------
// GEMM1 (K=64): fully direct — A and B fragments read straight from global.
__global__ __launch_bounds__(256) void gemm1_direct(const __hip_bfloat16* __restrict__ A,
                                                    const __hip_bfloat16* __restrict__ BT,
                                                    const float* __restrict__ bias,
                                                    __hip_bfloat16* __restrict__ C) {
    const int orig = blockIdx.x;
    const int L = (orig & 7) * CPX + (orig >> 3);
    const int mb = L >> 2, nb = L & 3;

    const int tid = threadIdx.x;
    const int lane = tid & 63;
    const int w = tid >> 6;
    const int wm = w >> 1, wn = w & 1;
    const long long rbase = (long long)mb * 128;
    const int nbase = nb * 128;
    const int lo = lane & 15, hi = lane >> 4;

    f32x4 acc[4][4];
#pragma unroll
    for (int i = 0; i < 4; ++i)
#pragma unroll
        for (int j = 0; j < 4; ++j) acc[i][j] = (f32x4){0.f, 0.f, 0.f, 0.f};

#pragma unroll
    for (int ks = 0; ks < 2; ++ks) {
        bf16x8 af[4], bfr[4];
#pragma unroll
        for (int mi = 0; mi < 4; ++mi)
            af[mi] = *(const bf16x8*)&A[(rbase + wm * 64 + mi * 16 + lo) * NF +
                                        ks * 32 + hi * 8];
#pragma unroll
        for (int ni = 0; ni < 4; ++ni)
            bfr[ni] = *(const bf16x8*)&BT[(long long)(nbase + wn * 64 + ni * 16 + lo) * NF +
                                          ks * 32 + hi * 8];
#pragma unroll
        for (int mi = 0; mi < 4; ++mi)
#pragma unroll
            for (int ni = 0; ni < 4; ++ni)
                acc[mi][ni] = __builtin_amdgcn_mfma_f32_16x16x32_bf16(
                    af[mi], bfr[ni], acc[mi][ni], 0, 0, 0);
    }

    const int col0 = nbase + wn * 64 + lo;
    const long long row00 = rbase + wm * 64 + hi * 4;
#pragma unroll
    for (int ni = 0; ni < 4; ++ni) {
        int col = col0 + ni * 16;
        float bv = bias[col];
#pragma unroll
        for (int mi = 0; mi < 4; ++mi) {
            long long r0 = row00 + mi * 16;
#pragma unroll
            for (int r = 0; r < 4; ++r) {
                float v = fmaxf(acc[mi][ni][r] + bv, 0.f);   // ReLU
                C[(r0 + r) * NH + col] = __float2bfloat16(v);
            }
        }
    }
}

// ---------------------------------------------------------------------------
// GEMM2 (K=512): counted-vmcnt 2-deep pipeline (T3/T4 minimum form).
__global__ __launch_bounds__(256) void gemm2_db(const __hip_bfloat16* __restrict__ A,
                                                const __hip_bfloat16* __restrict__ BT,
                                                const float* __restrict__ bias,
                                                __hip_bfloat16* __restrict__ C,
                                                float* __restrict__ partial) {
    constexpr int BK = 64;
    __shared__ __align__(16) char smem[65536];   // 2 sets x (A 16KB | B 16KB)
    float* smsum = (float*)smem;                 // alias set0 (dead after loop)
    float* smsq  = (float*)(smem + 2048);

    const int orig = blockIdx.x;
    const int L = (orig & 7) * CPX + (orig >> 3);
    const int mb = L >> 2, nb = L & 3;

    const int tid = threadIdx.x;
    const int lane = tid & 63;
    const int w = tid >> 6;
    const int wm = w >> 1, wn = w & 1;
    const long long rbase = (long long)mb * 128;
    const int nbase = nb * 128;
    const int r8  = lane >> 3;            // stage row within 8-row group
    const int swc = (lane & 7) ^ r8;      // pre-swizzled global chunk (rule #21)
    const int key = lane & 7;             // read-side swizzle key
    const int lo = lane & 15, hi = lane >> 4;

    const __hip_bfloat16* gaBase =
        A + (rbase + w * 32 + r8) * (long long)NH + swc * 8;
    const __hip_bfloat16* gbBase =
        BT + (long long)(nbase + w * 32 + r8) * NH + swc * 8;
    const int laOff = (w * 32) * BK;

    auto STAGE = [&](int s, int kb) {
        __hip_bfloat16* la = (__hip_bfloat16*)(smem + s * 32768) + laOff;
        __hip_bfloat16* lb = (__hip_bfloat16*)(smem + s * 32768 + 16384) + laOff;
#pragma unroll
        for (int t = 0; t < 4; ++t)
            GLOAD16(gaBase + kb + (long long)t * 8 * NH, la + t * 8 * BK);
#pragma unroll
        for (int t = 0; t < 4; ++t)
            GLOAD16(gbBase + kb + (long long)t * 8 * NH, lb + t * 8 * BK);
    };

    f32x4 acc[4][4];
#pragma unroll
    for (int i = 0; i < 4; ++i)
#pragma unroll
        for (int j = 0; j < 4; ++j) acc[i][j] = (f32x4){0.f, 0.f, 0.f, 0.f};

    // prologue: 2-deep prefetch (16 loads outstanding per wave)
    STAGE(0, 0);
    STAGE(1, BK);

#pragma unroll
    for (int t = 0; t < 8; ++t) {
        if (t == 7) { asm volatile("s_waitcnt vmcnt(0)" ::: "memory"); }
        else        { asm volatile("s_waitcnt vmcnt(8)" ::: "memory"); }
        __builtin_amdgcn_s_barrier();          // all waves' DMA for cur landed
        __builtin_amdgcn_sched_barrier(0);

        const __hip_bfloat16* Ac = (const __hip_bfloat16*)(smem + (t & 1) * 32768);
        const __hip_bfloat16* Bc = Ac + 8192;  // +16384 bytes
#pragma unroll
        for (int ks = 0; ks < 2; ++ks) {
            bf16x8 af[4], bfr[4];
#pragma unroll
            for (int mi = 0; mi < 4; ++mi)
                af[mi] = *(const bf16x8*)&Ac[(wm * 64 + mi * 16 + lo) * BK +
                                             (((ks * 4 + hi) ^ key) * 8)];
#pragma unroll
            for (int ni = 0; ni < 4; ++ni)
                bfr[ni] = *(const bf16x8*)&Bc[(wn * 64 + ni * 16 + lo) * BK +
                                              (((ks * 4 + hi) ^ key) * 8)];
#pragma unroll
            for (int mi = 0; mi < 4; ++mi)
#pragma unroll
                for (int ni = 0; ni < 4; ++ni)
                    acc[mi][ni] = __builtin_amdgcn_mfma_f32_16x16x32_bf16(
                        af[mi], bfr[ni], acc[mi][ni], 0, 0, 0);
        }
        __builtin_amdgcn_sched_barrier(0);
        __builtin_amdgcn_s_barrier();          // all waves done reading cur
        __builtin_amdgcn_sched_barrier(0);
        if (t < 6) STAGE(t & 1, (t + 2) * BK); // refill freed buffer, 2 ahead
    }

    // epilogue: vmcnt==0 here; full barrier before LDS alias reuse
    __syncthreads();
    if (tid < 128) { smsum[tid] = 0.f; smsq[tid] = 0.f; }
    __syncthreads();
    const int col0 = nbase + wn * 64 + lo;
    const long long row00 = rbase + wm * 64 + hi * 4;
#pragma unroll
    for (int ni = 0; ni < 4; ++ni) {
        int col = col0 + ni * 16;
        float bv = bias[col];
        float s = 0.f, q = 0.f;
#pragma unroll
        for (int mi = 0; mi < 4; ++mi) {
            long long r0 = row00 + mi * 16;
#pragma unroll
            for (int r = 0; r < 4; ++r) {
                float v = acc[mi][ni][r] + bv;
                C[(r0 + r) * NH + col] = __float2bfloat16(v);
                if ((r0 + r) < NN) { s += v; q += v * v; }
            }
        }
        s += __shfl_xor(s, 16); s += __shfl_xor(s, 32);
        q += __shfl_xor(q, 16); q += __shfl_xor(q, 32);
        if (lane < 16) {
            atomicAdd(&smsum[wn * 64 + ni * 16 + lane], s);
            atomicAdd(&smsq[wn * 64 + ni * 16 + lane], q);
        }
    }
    __syncthreads();
    if (tid < 128) {
        partial[mb * 1024 + nbase + tid] = smsum[tid];
        partial[mb * 1024 + 512 + nbase + tid] = smsq[tid];
    }
}

// reduce per-block partials: stats[j] = sum_mb partial[mb*1024 + j], j<1024
__global__ __launch_bounds__(256) void stats_reduce(const float* __restrict__ partial,
                                                    float* __restrict__ stats) {
    int j = blockIdx.x * 256 + threadIdx.x;   // 0..1023
    float s = 0.f;
    for (int mb = 0; mb < MB; ++mb) s += partial[mb * 1024 + j];
    stats[j] = s;
}

// BN(train stats) + ReLU + classifier fused; bf16 h2, per-lane register params
__global__ __launch_bounds__(256) void bn_cls(const __hip_bfloat16* __restrict__ h2b,
                                              const float* __restrict__ stats,
                                              const float* __restrict__ gamma,
                                              const float* __restrict__ beta,
                                              const float* __restrict__ Wc,
                                              const float* __restrict__ bc,
                                              float* __restrict__ out) {
    int tid = threadIdx.x;
    int lane = tid & 63;
    int k0 = lane * 8;
    float sc[8], sh[8], w0[8], w1[8];
#pragma unroll
    for (int j = 0; j < 8; ++j) {
        int k = k0 + j;
        float mean = stats[k] * (1.0f / NN);
        float var = stats[512 + k] * (1.0f / NN) - mean * mean;
        float rs = rsqrtf(var + 1e-5f);
        float s = gamma[k] * rs;
        sc[j] = s;
        sh[j] = beta[k] - mean * s;
        w0[j] = Wc[2 * k];
        w1[j] = Wc[2 * k + 1];
    }
    float bc0 = bc[0], bc1 = bc[1];
    int wid = blockIdx.x * 4 + (tid >> 6);
    int nw = gridDim.x * 4;
    for (int row = wid; row < NN; row += nw) {
        bf16x8 v8 = *(const bf16x8*)&h2b[(long long)row * NH + k0];
        float a0 = 0.f, a1 = 0.f;
#pragma unroll
        for (int j = 0; j < 8; ++j) {
            float v = __bfloat162float(((const __hip_bfloat16*)&v8)[j]);
            float hn = fmaxf(fmaf(v, sc[j], sh[j]), 0.f);
            a0 = fmaf(hn, w0[j], a0);
            a1 = fmaf(hn, w1[j], a1);
        }
#pragma unroll
        for (int off = 32; off; off >>= 1) {
            a0 += __shfl_xor(a0, off);
            a1 += __shfl_xor(a1, off);
        }
        if (lane == 0) {
            out[(long long)row * 2 + 0] = a0 + bc0;
            out[(long long)row * 2 + 1] = a1 + bc1;
        }
    }
}

// ---------------------------------------------------------------------------
extern "C" void kernel_launch(void* const* d_in, const int* in_sizes, int n_in,
                              void* d_out, int out_size, void* d_ws, size_t ws_size,
                              hipStream_t stream) {
    const float* x     = (const float*)d_in[0];
    const void*  ei    = d_in[1];
    const float* W1    = (const float*)d_in[2];
    const float* b1    = (const float*)d_in[3];
    const float* W2    = (const float*)d_in[4];
    const float* b2    = (const float*)d_in[5];
    const float* gamma = (const float*)d_in[6];
    const float* beta  = (const float*)d_in[7];
    const float* Wc    = (const float*)d_in[8];
    const float* bc    = (const float*)d_in[9];
    float* out = (float*)d_out;

    // workspace carve-up (256B aligned)
    char* base = (char*)d_ws;
    size_t o = 0;
    auto alloc = [&](size_t bytes) {
        char* p = base + o;
        o = (o + bytes + 255) & ~(size_t)255;
        return p;
    };
    __hip_bfloat16* h0b     = (__hip_bfloat16*)alloc((size_t)MP * NF * 2);
    __hip_bfloat16* h1b     = (__hip_bfloat16*)alloc((size_t)MP * NH * 2);
    __hip_bfloat16* h2b     = (__hip_bfloat16*)alloc((size_t)MP * NH * 2);
    __hip_bfloat16* xb      = (__hip_bfloat16*)alloc((size_t)NN * NF * 2);
    __hip_bfloat16* w1t     = (__hip_bfloat16*)alloc((size_t)NH * NF * 2);
    __hip_bfloat16* w2t     = (__hip_bfloat16*)alloc((size_t)NH * NH * 2);
    int*            ebS     = (int*)alloc((size_t)NBK * EBCAP * 4);
    int*            ebD     = (int*)alloc((size_t)NBK * EBCAP * 4);
    int*            bcnt    = (int*)alloc(256 * 4);
    int*            bbase   = (int*)alloc(256 * 4);
    int*            rowptr  = (int*)alloc((size_t)(NN + 1) * 4);
    int*            csr     = (int*)alloc((size_t)NE * 4);
    float*          partial = (float*)alloc((size_t)MB * 1024 * 4);
    float*          stats   = (float*)alloc(1024 * 4);
    int*            flag    = (int*)alloc(256);

    hipMemsetAsync(bcnt, 0, NBK * 4, stream);
    detect_idx<<<1, 1, 0, stream>>>((const int*)ei, flag);

    // CSR build via 2-pass LDS bucket sort (no scattered global atomics)
    bucketA<<<ABLK, 256, 0, stream>>>(ei, flag, bcnt, ebS, ebD);
    scan_bsum<<<1, 256, 0, stream>>>(bcnt, bbase);
    bucketB<<<NBK, 256, 0, stream>>>(ebS, ebD, bcnt, bbase, rowptr, csr);

    cvt_x<<<(NN * NF / 4 + 255) / 256, 256, 0, stream>>>(x, xb);
    gather<<<MP / 4, 256, 0, stream>>>(xb, rowptr, csr, h0b);

    cvt_wt<<<(NF * NH + 255) / 256, 256, 0, stream>>>(W1, w1t, NF, NH);
    cvt_wt<<<(NH * NH + 255) / 256, 256, 0, stream>>>(W2, w2t, NH, NH);

    gemm1_direct<<<GRID, 256, 0, stream>>>(h0b, w1t, b1, h1b);
    gemm2_db<<<GRID, 256, 0, stream>>>(h1b, w2t, b2, h2b, partial);

    stats_reduce<<<4, 256, 0, stream>>>(partial, stats);
    bn_cls<<<512, 256, 0, stream>>>(h2b, stats, gamma, beta, Wc, bc, out);
}

// Round 14
// 179.673 us; speedup vs baseline: 1.4494x; 1.0005x over previous
//
#include <hip/hip_runtime.h>
#include <hip/hip_bf16.h>

#define NN 50000      // nodes
#define MP 50176      // padded nodes (392 * 128 = 196 * 256)
#define NF 64         // features
#define NH 512        // hidden
#define NE 800000     // edges
#define NBK 196       // dst buckets (dst >> 8)
#define EBCAP 8192    // per-bucket capacity (2x Poisson mean 4082, sd 64)
#define ABLK 391      // bucketA blocks (x 2048 edges)
#define MB 392        // 128-row M blocks (gemm1 grid)
#define MBB 196       // 256-row M blocks (gemm2 grid)
#define GRID (MB * 4) // 1568 = 8 * 196
#define CPX (GRID / 8)
#define G2GRID (MBB * 2)   // 392 = 8 * 49
#define CPX2 (G2GRID / 8)  // 49

typedef __attribute__((ext_vector_type(8))) short bf16x8;
typedef __attribute__((ext_vector_type(4))) float f32x4;

#define GLOAD16(g, l)                                                        \
    __builtin_amdgcn_global_load_lds(                                        \
        (const __attribute__((address_space(1))) unsigned int*)(g),          \
        (__attribute__((address_space(3))) unsigned int*)(l), 16, 0, 0)

// ---------------------------------------------------------------------------
// detect whether edge_index is int64 (high dwords all zero) or int32
__global__ void detect_idx(const int* __restrict__ ei, int* __restrict__ flag) {
    if (threadIdx.x == 0 && blockIdx.x == 0) {
        int any = 0;
        for (int i = 0; i < 32; ++i) any |= ei[2 * i + 1];
        *flag = (any == 0) ? 1 : 0;   // 1 => int64 layout
    }
}

// ---------------------------------------------------------------------------
// Bucket sort pass A: partition edges into 196 dst-buckets (dst>>8).
__global__ __launch_bounds__(256) void bucketA(const void* __restrict__ eiv,
                                               const int* __restrict__ flag,
                                               int* __restrict__ bcnt,
                                               int* __restrict__ ebS,
                                               int* __restrict__ ebD) {
    __shared__ int hist[NBK];
    __shared__ int lcur[NBK];
    const int tid = threadIdx.x;
    const int chunk = blockIdx.x * 2048;
    const int lim = min(2048, NE - chunk);
    const bool is64 = (*flag != 0);
    const long long* ei64 = (const long long*)eiv;
    const int* ei32 = (const int*)eiv;

    for (int i = tid; i < NBK; i += 256) hist[i] = 0;
    __syncthreads();
    for (int i = tid; i < lim; i += 256) {
        int d = is64 ? (int)ei64[NE + chunk + i] : ei32[NE + chunk + i];
        atomicAdd(&hist[d >> 8], 1);
    }
    __syncthreads();
    for (int i = tid; i < NBK; i += 256) {
        int c = hist[i];
        lcur[i] = c ? atomicAdd(&bcnt[i], c) : 0;   // reserve run in bucket i
    }
    __syncthreads();
    for (int i = tid; i < lim; i += 256) {
        int s, d;
        if (is64) { s = (int)ei64[chunk + i]; d = (int)ei64[NE + chunk + i]; }
        else      { s = ei32[chunk + i];      d = ei32[NE + chunk + i]; }
        int b = d >> 8;
        int p = atomicAdd(&lcur[b], 1);             // LDS cursor -> global slot
        ebS[b * EBCAP + p] = s;
        ebD[b * EBCAP + p] = d;
    }
}

// exclusive scan of the NBK bucket counts (1 block) -> bucket bases
__global__ __launch_bounds__(256) void scan_bsum(const int* __restrict__ bsum,
                                                 int* __restrict__ boff) {
    __shared__ int sm[256];
    int tid = threadIdx.x;
    int v = (tid < NBK) ? bsum[tid] : 0;
    sm[tid] = v;
    __syncthreads();
    int acc = v;
#pragma unroll
    for (int off = 1; off < 256; off <<= 1) {
        int t = (tid >= off) ? sm[tid - off] : 0;
        __syncthreads();
        acc += t;
        sm[tid] = acc;
        __syncthreads();
    }
    if (tid < NBK) boff[tid] = acc - v;         // exclusive
}

// Bucket sort pass B: one block per bucket; LDS counting sort -> rowptr, csr.
__global__ __launch_bounds__(256) void bucketB(const int* __restrict__ ebS,
                                               const int* __restrict__ ebD,
                                               const int* __restrict__ bcnt,
                                               const int* __restrict__ bbase,
                                               int* __restrict__ rowptr,
                                               int* __restrict__ csr) {
    __shared__ int hist[256], sm[256], curs[256];
    const int b = blockIdx.x;
    const int tid = threadIdx.x;
    const int n0 = b << 8;
    const int cnt = bcnt[b];
    const int base = bbase[b];

    hist[tid] = 0;
    __syncthreads();
    for (int i = tid; i < cnt; i += 256)
        atomicAdd(&hist[ebD[b * EBCAP + i] & 255], 1);
    __syncthreads();
    int v = hist[tid];
    sm[tid] = v;
    __syncthreads();
    int acc = v;
#pragma unroll
    for (int off = 1; off < 256; off <<= 1) {
        int t = (tid >= off) ? sm[tid - off] : 0;
        __syncthreads();
        acc += t;
        sm[tid] = acc;
        __syncthreads();
    }
    int excl = acc - v;
    if (n0 + tid < NN) rowptr[n0 + tid] = base + excl;   // coalesced
    curs[tid] = excl;
    __syncthreads();
    for (int i = tid; i < cnt; i += 256) {
        int s = ebS[b * EBCAP + i];
        int d = ebD[b * EBCAP + i] & 255;
        int lp = atomicAdd(&curs[d], 1);                 // LDS cursor
        csr[base + lp] = s;
    }
    if (b == 0 && tid == 0) rowptr[NN] = NE;
}

// x fp32 -> bf16 (halves gather's L3-resident re-read stream)
__global__ __launch_bounds__(256) void cvt_x(const float* __restrict__ x,
                                             __hip_bfloat16* __restrict__ xb) {
    int t = blockIdx.x * 256 + threadIdx.x;
    if (t >= NN * NF / 4) return;
    float4 v = *(const float4*)&x[t * 4];
    union { ushort4 u; __hip_bfloat16 h[4]; } o;
    o.h[0] = __float2bfloat16(v.x);
    o.h[1] = __float2bfloat16(v.y);
    o.h[2] = __float2bfloat16(v.z);
    o.h[3] = __float2bfloat16(v.w);
    *(ushort4*)&xb[t * 4] = o.u;
}

// gather-sum, one WAVE per node (lane = feature), bf16 x rows, fp32 accum.
__global__ __launch_bounds__(256) void gather(const __hip_bfloat16* __restrict__ xb,
                                              const int* __restrict__ rowptr,
                                              const int* __restrict__ csr,
                                              __hip_bfloat16* __restrict__ h0b) {
    int n = blockIdx.x * 4 + (threadIdx.x >> 6);   // node id
    int lane = threadIdx.x & 63;
    if (n >= MP) return;
    if (n >= NN) {
        h0b[(long long)n * NF + lane] = __float2bfloat16(0.f);
        return;
    }
    float acc = __bfloat162float(xb[(long long)n * NF + lane]);
    int e = rowptr[n], e1 = rowptr[n + 1];
    for (; e + 4 <= e1; e += 4) {
        int s0 = csr[e], s1 = csr[e + 1], s2 = csr[e + 2], s3 = csr[e + 3];
        float v0 = __bfloat162float(xb[(long long)s0 * NF + lane]);
        float v1 = __bfloat162float(xb[(long long)s1 * NF + lane]);
        float v2 = __bfloat162float(xb[(long long)s2 * NF + lane]);
        float v3 = __bfloat162float(xb[(long long)s3 * NF + lane]);
        acc += (v0 + v1) + (v2 + v3);
    }
    for (; e < e1; ++e) acc += __bfloat162float(xb[(long long)csr[e] * NF + lane]);
    h0b[(long long)n * NF + lane] = __float2bfloat16(acc);
}

// W [K][N] fp32 -> WT [N][K] bf16
__global__ __launch_bounds__(256) void cvt_wt(const float* __restrict__ W,
                                              __hip_bfloat16* __restrict__ WT,
                                              int K, int N) {
    int t = blockIdx.x * 256 + threadIdx.x;
    if (t >= K * N) return;
    int n = t % N, k = t / N;
    WT[n * K + k] = __float2bfloat16(W[t]);
}

// ---------------------------------------------------------------------------
// GEMM1 (K=64): fully direct — A and B fragments read straight from global.
__global__ __launch_bounds__(256) void gemm1_direct(const __hip_bfloat16* __restrict__ A,
                                                    const __hip_bfloat16* __restrict__ BT,
                                                    const float* __restrict__ bias,
                                                    __hip_bfloat16* __restrict__ C) {
    const int orig = blockIdx.x;
    const int L = (orig & 7) * CPX + (orig >> 3);
    const int mb = L >> 2, nb = L & 3;

    const int tid = threadIdx.x;
    const int lane = tid & 63;
    const int w = tid >> 6;
    const int wm = w >> 1, wn = w & 1;
    const long long rbase = (long long)mb * 128;
    const int nbase = nb * 128;
    const int lo = lane & 15, hi = lane >> 4;

    f32x4 acc[4][4];
#pragma unroll
    for (int i = 0; i < 4; ++i)
#pragma unroll
        for (int j = 0; j < 4; ++j) acc[i][j] = (f32x4){0.f, 0.f, 0.f, 0.f};

#pragma unroll
    for (int ks = 0; ks < 2; ++ks) {
        bf16x8 af[4], bfr[4];
#pragma unroll
        for (int mi = 0; mi < 4; ++mi)
            af[mi] = *(const bf16x8*)&A[(rbase + wm * 64 + mi * 16 + lo) * NF +
                                        ks * 32 + hi * 8];
#pragma unroll
        for (int ni = 0; ni < 4; ++ni)
            bfr[ni] = *(const bf16x8*)&BT[(long long)(nbase + wn * 64 + ni * 16 + lo) * NF +
                                          ks * 32 + hi * 8];
#pragma unroll
        for (int mi = 0; mi < 4; ++mi)
#pragma unroll
            for (int ni = 0; ni < 4; ++ni)
                acc[mi][ni] = __builtin_amdgcn_mfma_f32_16x16x32_bf16(
                    af[mi], bfr[ni], acc[mi][ni], 0, 0, 0);
    }

    const int col0 = nbase + wn * 64 + lo;
    const long long row00 = rbase + wm * 64 + hi * 4;
#pragma unroll
    for (int ni = 0; ni < 4; ++ni) {
        int col = col0 + ni * 16;
        float bv = bias[col];
#pragma unroll
        for (int mi = 0; mi < 4; ++mi) {
            long long r0 = row00 + mi * 16;
#pragma unroll
            for (int r = 0; r < 4; ++r) {
                float v = fmaxf(acc[mi][ni][r] + bv, 0.f);   // ReLU
                C[(r0 + r) * NH + col] = __float2bfloat16(v);
            }
        }
    }
}

// ---------------------------------------------------------------------------
// GEMM2 (K=512): 256x256 tile, 512 threads (8 waves 2m x 4n), BK=64,
// counted-vmcnt 2-deep pipeline. Halves staged L2/L3 traffic vs the 128^2
// tile (200 MB vs 400 MB) and doubles MFMA per staged byte. LDS = 2 sets x
// (A 32KB | B 32KB) = 128 KB -> 1 block/CU; pipeline ILP substitutes for TLP.
__global__ __launch_bounds__(512) void gemm2_256(const __hip_bfloat16* __restrict__ A,
                                                 const __hip_bfloat16* __restrict__ BT,
                                                 const float* __restrict__ bias,
                                                 __hip_bfloat16* __restrict__ C,
                                                 float* __restrict__ partial) {
    constexpr int BK = 64;
    __shared__ __align__(16) char smem[131072];  // 2 sets x (A 32KB | B 32KB)
    float* smsum = (float*)smem;                 // alias set0 (dead after loop)
    float* smsq  = (float*)(smem + 2048);

    const int orig = blockIdx.x;                 // grid 392 = 8 * 49
    const int L = (orig & 7) * CPX2 + (orig >> 3);
    const int mbb = L >> 1, nbb = L & 1;         // 2 nbb siblings same XCD

    const int tid = threadIdx.x;
    const int lane = tid & 63;
    const int w = tid >> 6;                      // wave 0..7
    const int wm = w >> 2, wn = w & 3;           // 2m x 4n
    const long long rbase = (long long)mbb * 256;
    const int nbase = nbb * 256;
    const int r8  = lane >> 3;            // stage row within 8-row group
    const int swc = (lane & 7) ^ r8;      // pre-swizzled global chunk (rule #21)
    const int key = lane & 7;             // read-side swizzle key
    const int lo = lane & 15, hi = lane >> 4;

    const __hip_bfloat16* gaBase =
        A + (rbase + w * 32 + r8) * (long long)NH + swc * 8;
    const __hip_bfloat16* gbBase =
        BT + (long long)(nbase + w * 32 + r8) * NH + swc * 8;
    const int laOff = (w * 32) * BK;

    auto STAGE = [&](int s, int kb) {
        __hip_bfloat16* la = (__hip_bfloat16*)(smem + s * 65536) + laOff;
        __hip_bfloat16* lb = (__hip_bfloat16*)(smem + s * 65536 + 32768) + laOff;
#pragma unroll
        for (int t = 0; t < 4; ++t)
            GLOAD16(gaBase + kb + (long long)t * 8 * NH, la + t * 8 * BK);
#pragma unroll
        for (int t = 0; t < 4; ++t)
            GLOAD16(gbBase + kb + (long long)t * 8 * NH, lb + t * 8 * BK);
    };

    f32x4 acc[8][4];
#pragma unroll
    for (int i = 0; i < 8; ++i)
#pragma unroll
        for (int j = 0; j < 4; ++j) acc[i][j] = (f32x4){0.f, 0.f, 0.f, 0.f};

    // prologue: 2-deep prefetch (16 loads outstanding per wave)
    STAGE(0, 0);
    STAGE(1, BK);

#pragma unroll
    for (int t = 0; t < 8; ++t) {
        if (t == 7) { asm volatile("s_waitcnt vmcnt(0)" ::: "memory"); }
        else        { asm volatile("s_waitcnt vmcnt(8)" ::: "memory"); }
        __builtin_amdgcn_s_barrier();          // all waves' DMA for cur landed
        __builtin_amdgcn_sched_barrier(0);

        const __hip_bfloat16* Ac = (const __hip_bfloat16*)(smem + (t & 1) * 65536);
        const __hip_bfloat16* Bc = Ac + 16384;  // +32768 bytes
#pragma unroll
        for (int ks = 0; ks < 2; ++ks) {
            bf16x8 af[8], bfr[4];
#pragma unroll
            for (int mi = 0; mi < 8; ++mi)
                af[mi] = *(const bf16x8*)&Ac[(wm * 128 + mi * 16 + lo) * BK +
                                             (((ks * 4 + hi) ^ key) * 8)];
#pragma unroll
            for (int ni = 0; ni < 4; ++ni)
                bfr[ni] = *(const bf16x8*)&Bc[(wn * 64 + ni * 16 + lo) * BK +
                                              (((ks * 4 + hi) ^ key) * 8)];
#pragma unroll
            for (int mi = 0; mi < 8; ++mi)
#pragma unroll
                for (int ni = 0; ni < 4; ++ni)
                    acc[mi][ni] = __builtin_amdgcn_mfma_f32_16x16x32_bf16(
                        af[mi], bfr[ni], acc[mi][ni], 0, 0, 0);
        }
        __builtin_amdgcn_sched_barrier(0);
        __builtin_amdgcn_s_barrier();          // all waves done reading cur
        __builtin_amdgcn_sched_barrier(0);
        if (t < 6) STAGE(t & 1, (t + 2) * BK); // refill freed buffer, 2 ahead
    }

    // epilogue: vmcnt==0 here; full barrier before LDS alias reuse
    __syncthreads();
    if (tid < 256) { smsum[tid] = 0.f; smsq[tid] = 0.f; }
    __syncthreads();
    const int col0 = nbase + wn * 64 + lo;
    const long long row00 = rbase + wm * 128 + hi * 4;
#pragma unroll
    for (int ni = 0; ni < 4; ++ni) {
        int col = col0 + ni * 16;
        float bv = bias[col];
        float s = 0.f, q = 0.f;
#pragma unroll
        for (int mi = 0; mi < 8; ++mi) {
            long long r0 = row00 + mi * 16;
#pragma unroll
            for (int r = 0; r < 4; ++r) {
                float v = acc[mi][ni][r] + bv;
                C[(r0 + r) * NH + col] = __float2bfloat16(v);
                if ((r0 + r) < NN) { s += v; q += v * v; }
            }
        }
        s += __shfl_xor(s, 16); s += __shfl_xor(s, 32);
        q += __shfl_xor(q, 16); q += __shfl_xor(q, 32);
        if (lane < 16) {   // col_local = wn*64 + ni*16 + lane; 2 wm-waves collide
            atomicAdd(&smsum[wn * 64 + ni * 16 + lane], s);
            atomicAdd(&smsq[wn * 64 + ni * 16 + lane], q);
        }
    }
    __syncthreads();
    if (tid < 256) {
        partial[mbb * 1024 + nbase + tid] = smsum[tid];
        partial[mbb * 1024 + 512 + nbase + tid] = smsq[tid];
    }
}

// reduce per-block partials: stats[j] = sum_mbb partial[mbb*1024 + j], j<1024
__global__ __launch_bounds__(256) void stats_reduce(const float* __restrict__ partial,
                                                    float* __restrict__ stats) {
    int j = blockIdx.x * 256 + threadIdx.x;   // 0..1023
    float s = 0.f;
    for (int mb = 0; mb < MBB; ++mb) s += partial[mb * 1024 + j];
    stats[j] = s;
}

// BN(train stats) + ReLU + classifier fused; bf16 h2, per-lane register params
__global__ __launch_bounds__(256) void bn_cls(const __hip_bfloat16* __restrict__ h2b,
                                              const float* __restrict__ stats,
                                              const float* __restrict__ gamma,
                                              const float* __restrict__ beta,
                                              const float* __restrict__ Wc,
                                              const float* __restrict__ bc,
                                              float* __restrict__ out) {
    int tid = threadIdx.x;
    int lane = tid & 63;
    int k0 = lane * 8;
    float sc[8], sh[8], w0[8], w1[8];
#pragma unroll
    for (int j = 0; j < 8; ++j) {
        int k = k0 + j;
        float mean = stats[k] * (1.0f / NN);
        float var = stats[512 + k] * (1.0f / NN) - mean * mean;
        float rs = rsqrtf(var + 1e-5f);
        float s = gamma[k] * rs;
        sc[j] = s;
        sh[j] = beta[k] - mean * s;
        w0[j] = Wc[2 * k];
        w1[j] = Wc[2 * k + 1];
    }
    float bc0 = bc[0], bc1 = bc[1];
    int wid = blockIdx.x * 4 + (tid >> 6);
    int nw = gridDim.x * 4;
    for (int row = wid; row < NN; row += nw) {
        bf16x8 v8 = *(const bf16x8*)&h2b[(long long)row * NH + k0];
        float a0 = 0.f, a1 = 0.f;
#pragma unroll
        for (int j = 0; j < 8; ++j) {
            float v = __bfloat162float(((const __hip_bfloat16*)&v8)[j]);
            float hn = fmaxf(fmaf(v, sc[j], sh[j]), 0.f);
            a0 = fmaf(hn, w0[j], a0);
            a1 = fmaf(hn, w1[j], a1);
        }
#pragma unroll
        for (int off = 32; off; off >>= 1) {
            a0 += __shfl_xor(a0, off);
            a1 += __shfl_xor(a1, off);
        }
        if (lane == 0) {
            out[(long long)row * 2 + 0] = a0 + bc0;
            out[(long long)row * 2 + 1] = a1 + bc1;
        }
    }
}

// ---------------------------------------------------------------------------
extern "C" void kernel_launch(void* const* d_in, const int* in_sizes, int n_in,
                              void* d_out, int out_size, void* d_ws, size_t ws_size,
                              hipStream_t stream) {
    const float* x     = (const float*)d_in[0];
    const void*  ei    = d_in[1];
    const float* W1    = (const float*)d_in[2];
    const float* b1    = (const float*)d_in[3];
    const float* W2    = (const float*)d_in[4];
    const float* b2    = (const float*)d_in[5];
    const float* gamma = (const float*)d_in[6];
    const float* beta  = (const float*)d_in[7];
    const float* Wc    = (const float*)d_in[8];
    const float* bc    = (const float*)d_in[9];
    float* out = (float*)d_out;

    // workspace carve-up (256B aligned)
    char* base = (char*)d_ws;
    size_t o = 0;
    auto alloc = [&](size_t bytes) {
        char* p = base + o;
        o = (o + bytes + 255) & ~(size_t)255;
        return p;
    };
    __hip_bfloat16* h0b     = (__hip_bfloat16*)alloc((size_t)MP * NF * 2);
    __hip_bfloat16* h1b     = (__hip_bfloat16*)alloc((size_t)MP * NH * 2);
    __hip_bfloat16* h2b     = (__hip_bfloat16*)alloc((size_t)MP * NH * 2);
    __hip_bfloat16* xb      = (__hip_bfloat16*)alloc((size_t)NN * NF * 2);
    __hip_bfloat16* w1t     = (__hip_bfloat16*)alloc((size_t)NH * NF * 2);
    __hip_bfloat16* w2t     = (__hip_bfloat16*)alloc((size_t)NH * NH * 2);
    int*            ebS     = (int*)alloc((size_t)NBK * EBCAP * 4);
    int*            ebD     = (int*)alloc((size_t)NBK * EBCAP * 4);
    int*            bcnt    = (int*)alloc(256 * 4);
    int*            bbase   = (int*)alloc(256 * 4);
    int*            rowptr  = (int*)alloc((size_t)(NN + 1) * 4);
    int*            csr     = (int*)alloc((size_t)NE * 4);
    float*          partial = (float*)alloc((size_t)MBB * 1024 * 4);
    float*          stats   = (float*)alloc(1024 * 4);
    int*            flag    = (int*)alloc(256);

    hipMemsetAsync(bcnt, 0, NBK * 4, stream);
    detect_idx<<<1, 1, 0, stream>>>((const int*)ei, flag);

    // CSR build via 2-pass LDS bucket sort (no scattered global atomics)
    bucketA<<<ABLK, 256, 0, stream>>>(ei, flag, bcnt, ebS, ebD);
    scan_bsum<<<1, 256, 0, stream>>>(bcnt, bbase);
    bucketB<<<NBK, 256, 0, stream>>>(ebS, ebD, bcnt, bbase, rowptr, csr);

    cvt_x<<<(NN * NF / 4 + 255) / 256, 256, 0, stream>>>(x, xb);
    gather<<<MP / 4, 256, 0, stream>>>(xb, rowptr, csr, h0b);

    cvt_wt<<<(NF * NH + 255) / 256, 256, 0, stream>>>(W1, w1t, NF, NH);
    cvt_wt<<<(NH * NH + 255) / 256, 256, 0, stream>>>(W2, w2t, NH, NH);

    gemm1_direct<<<GRID, 256, 0, stream>>>(h0b, w1t, b1, h1b);
    gemm2_256<<<G2GRID, 512, 0, stream>>>(h1b, w2t, b2, h2b, partial);

    stats_reduce<<<4, 256, 0, stream>>>(partial, stats);
    bn_cls<<<512, 256, 0, stream>>>(h2b, stats, gamma, beta, Wc, bc, out);
}

// Round 15
// 167.360 us; speedup vs baseline: 1.5560x; 1.0736x over previous
//
#include <hip/hip_runtime.h>
#include <hip/hip_bf16.h>

#define NN 50000      // nodes
#define MP 50176      // padded nodes (392 * 128)
#define NF 64         // features
#define NH 512        // hidden
#define NE 800000     // edges
#define NBK 196       // dst buckets (dst >> 8)
#define EBCAP 8192    // per-bucket capacity (2x Poisson mean 4082, sd 64)
#define ABLK 391      // bucketA blocks (x 2048 edges)
#define MB 392        // M blocks = MP/128
#define GRID (MB * 4) // 1568 = 8 * 196
#define CPX (GRID / 8)

typedef __attribute__((ext_vector_type(8))) short bf16x8;
typedef __attribute__((ext_vector_type(4))) float f32x4;

#define GLOAD16(g, l)                                                        \
    __builtin_amdgcn_global_load_lds(                                        \
        (const __attribute__((address_space(1))) unsigned int*)(g),          \
        (__attribute__((address_space(3))) unsigned int*)(l), 16, 0, 0)

// ---------------------------------------------------------------------------
// detect whether edge_index is int64 (high dwords all zero) or int32
__global__ void detect_idx(const int* __restrict__ ei, int* __restrict__ flag) {
    if (threadIdx.x == 0 && blockIdx.x == 0) {
        int any = 0;
        for (int i = 0; i < 32; ++i) any |= ei[2 * i + 1];
        *flag = (any == 0) ? 1 : 0;   // 1 => int64 layout
    }
}

// ---------------------------------------------------------------------------
// Bucket sort pass A: partition edges into 196 dst-buckets (dst>>8).
// Payload packed into one int: (dst&255)<<16 | src  (src < 50000 < 2^16).
__global__ __launch_bounds__(256) void bucketA(const void* __restrict__ eiv,
                                               const int* __restrict__ flag,
                                               int* __restrict__ bcnt,
                                               int* __restrict__ ebP) {
    __shared__ int hist[NBK];
    __shared__ int lcur[NBK];
    const int tid = threadIdx.x;
    const int chunk = blockIdx.x * 2048;
    const int lim = min(2048, NE - chunk);
    const bool is64 = (*flag != 0);
    const long long* ei64 = (const long long*)eiv;
    const int* ei32 = (const int*)eiv;

    for (int i = tid; i < NBK; i += 256) hist[i] = 0;
    __syncthreads();
    for (int i = tid; i < lim; i += 256) {
        int d = is64 ? (int)ei64[NE + chunk + i] : ei32[NE + chunk + i];
        atomicAdd(&hist[d >> 8], 1);
    }
    __syncthreads();
    for (int i = tid; i < NBK; i += 256) {
        int c = hist[i];
        lcur[i] = c ? atomicAdd(&bcnt[i], c) : 0;   // reserve run in bucket i
    }
    __syncthreads();
    for (int i = tid; i < lim; i += 256) {
        int s, d;
        if (is64) { s = (int)ei64[chunk + i]; d = (int)ei64[NE + chunk + i]; }
        else      { s = ei32[chunk + i];      d = ei32[NE + chunk + i]; }
        int b = d >> 8;
        int p = atomicAdd(&lcur[b], 1);             // LDS cursor -> global slot
        ebP[b * EBCAP + p] = ((d & 255) << 16) | s;
    }
}

// exclusive scan of the NBK bucket counts (1 block) -> bucket bases
__global__ __launch_bounds__(256) void scan_bsum(const int* __restrict__ bsum,
                                                 int* __restrict__ boff) {
    __shared__ int sm[256];
    int tid = threadIdx.x;
    int v = (tid < NBK) ? bsum[tid] : 0;
    sm[tid] = v;
    __syncthreads();
    int acc = v;
#pragma unroll
    for (int off = 1; off < 256; off <<= 1) {
        int t = (tid >= off) ? sm[tid - off] : 0;
        __syncthreads();
        acc += t;
        sm[tid] = acc;
        __syncthreads();
    }
    if (tid < NBK) boff[tid] = acc - v;         // exclusive
}

// Bucket sort pass B: one block per bucket; LDS counting sort -> rowptr, csr.
__global__ __launch_bounds__(256) void bucketB(const int* __restrict__ ebP,
                                               const int* __restrict__ bcnt,
                                               const int* __restrict__ bbase,
                                               int* __restrict__ rowptr,
                                               int* __restrict__ csr) {
    __shared__ int hist[256], sm[256], curs[256];
    const int b = blockIdx.x;
    const int tid = threadIdx.x;
    const int n0 = b << 8;
    const int cnt = bcnt[b];
    const int base = bbase[b];

    hist[tid] = 0;
    __syncthreads();
    for (int i = tid; i < cnt; i += 256)
        atomicAdd(&hist[(ebP[b * EBCAP + i] >> 16) & 255], 1);
    __syncthreads();
    int v = hist[tid];
    sm[tid] = v;
    __syncthreads();
    int acc = v;
#pragma unroll
    for (int off = 1; off < 256; off <<= 1) {
        int t = (tid >= off) ? sm[tid - off] : 0;
        __syncthreads();
        acc += t;
        sm[tid] = acc;
        __syncthreads();
    }
    int excl = acc - v;
    if (n0 + tid < NN) rowptr[n0 + tid] = base + excl;   // coalesced
    curs[tid] = excl;
    __syncthreads();
    for (int i = tid; i < cnt; i += 256) {
        int p = ebP[b * EBCAP + i];
        int lp = atomicAdd(&curs[(p >> 16) & 255], 1);   // LDS cursor
        csr[base + lp] = p & 0xFFFF;
    }
    if (b == 0 && tid == 0) rowptr[NN] = NE;
}

// one launch for all fp32->bf16 conversions: x, W1^T, W2^T
//   blocks [0, XBLK)            : xb[t] = bf16(x[t])           (float4 granular)
//   blocks [XBLK, XBLK+W1BLK)   : w1t[n][k] = bf16(W1[k][n])
//   blocks [XBLK+W1BLK, ...)    : w2t[n][k] = bf16(W2[k][n])
#define XBLK  (NN * NF / 4 / 256)        // 3125
#define W1BLK (NF * NH / 256)            // 128
#define W2BLK (NH * NH / 256)            // 1024
__global__ __launch_bounds__(256) void cvt_all(const float* __restrict__ x,
                                               const float* __restrict__ W1,
                                               const float* __restrict__ W2,
                                               __hip_bfloat16* __restrict__ xb,
                                               __hip_bfloat16* __restrict__ w1t,
                                               __hip_bfloat16* __restrict__ w2t) {
    int bb = blockIdx.x;
    if (bb < XBLK) {
        int t = bb * 256 + threadIdx.x;
        float4 v = *(const float4*)&x[t * 4];
        union { ushort4 u; __hip_bfloat16 h[4]; } o;
        o.h[0] = __float2bfloat16(v.x);
        o.h[1] = __float2bfloat16(v.y);
        o.h[2] = __float2bfloat16(v.z);
        o.h[3] = __float2bfloat16(v.w);
        *(ushort4*)&xb[t * 4] = o.u;
    } else if (bb < XBLK + W1BLK) {
        int t = (bb - XBLK) * 256 + threadIdx.x;   // over NF*NH
        int n = t % NH, k = t / NH;
        w1t[n * NF + k] = __float2bfloat16(W1[t]);
    } else {
        int t = (bb - XBLK - W1BLK) * 256 + threadIdx.x;   // over NH*NH
        int n = t % NH, k = t / NH;
        w2t[n * NH + k] = __float2bfloat16(W2[t]);
    }
}

// gather-sum, one WAVE per node (lane = feature), bf16 x rows, fp32 accum.
__global__ __launch_bounds__(256) void gather(const __hip_bfloat16* __restrict__ xb,
                                              const int* __restrict__ rowptr,
                                              const int* __restrict__ csr,
                                              __hip_bfloat16* __restrict__ h0b) {
    int n = blockIdx.x * 4 + (threadIdx.x >> 6);   // node id
    int lane = threadIdx.x & 63;
    if (n >= MP) return;
    if (n >= NN) {
        h0b[(long long)n * NF + lane] = __float2bfloat16(0.f);
        return;
    }
    float acc = __bfloat162float(xb[(long long)n * NF + lane]);
    int e = rowptr[n], e1 = rowptr[n + 1];
    for (; e + 4 <= e1; e += 4) {
        int s0 = csr[e], s1 = csr[e + 1], s2 = csr[e + 2], s3 = csr[e + 3];
        float v0 = __bfloat162float(xb[(long long)s0 * NF + lane]);
        float v1 = __bfloat162float(xb[(long long)s1 * NF + lane]);
        float v2 = __bfloat162float(xb[(long long)s2 * NF + lane]);
        float v3 = __bfloat162float(xb[(long long)s3 * NF + lane]);
        acc += (v0 + v1) + (v2 + v3);
    }
    for (; e < e1; ++e) acc += __bfloat162float(xb[(long long)csr[e] * NF + lane]);
    h0b[(long long)n * NF + lane] = __float2bfloat16(acc);
}

// ---------------------------------------------------------------------------
// GEMM1 (K=64): A staged via global_load_lds (issued first), B fragments read
// direct from L1-hot w1t while the DMA is in flight; single barrier.
__global__ __launch_bounds__(256) void gemm1_staged(const __hip_bfloat16* __restrict__ A,
                                                    const __hip_bfloat16* __restrict__ BT,
                                                    const float* __restrict__ bias,
                                                    __hip_bfloat16* __restrict__ C) {
    __shared__ __hip_bfloat16 As[128 * 64];   // 16 KB
    const int orig = blockIdx.x;
    const int L = (orig & 7) * CPX + (orig >> 3);
    const int mb = L >> 2, nb = L & 3;

    const int tid = threadIdx.x;
    const int lane = tid & 63;
    const int w = tid >> 6;
    const int wm = w >> 1, wn = w & 1;
    const long long rbase = (long long)mb * 128;
    const int nbase = nb * 128;
    const int r8  = lane >> 3;
    const int swc = (lane & 7) ^ r8;      // pre-swizzled global chunk (rule #21)
    const int key = lane & 7;
    const int lo = lane & 15, hi = lane >> 4;

    // issue A-tile DMA first
    {
        const __hip_bfloat16* ga = A + (rbase + w * 32 + r8) * NF + swc * 8;
        __hip_bfloat16* la = As + (w * 32) * 64;
#pragma unroll
        for (int t = 0; t < 4; ++t)
            GLOAD16(ga + t * 8 * NF, la + t * 8 * 64);
    }
    // B fragments direct from global (w1t 64 KB, L1/L2-hot) — hides DMA latency
    bf16x8 bfr[2][4];
#pragma unroll
    for (int ks = 0; ks < 2; ++ks)
#pragma unroll
        for (int ni = 0; ni < 4; ++ni)
            bfr[ks][ni] = *(const bf16x8*)&BT[(nbase + wn * 64 + ni * 16 + lo) * NF +
                                             ks * 32 + hi * 8];
    __syncthreads();   // A landed

    f32x4 acc[4][4];
#pragma unroll
    for (int i = 0; i < 4; ++i)
#pragma unroll
        for (int j = 0; j < 4; ++j) acc[i][j] = (f32x4){0.f, 0.f, 0.f, 0.f};

#pragma unroll
    for (int ks = 0; ks < 2; ++ks) {
        bf16x8 af[4];
#pragma unroll
        for (int mi = 0; mi < 4; ++mi)
            af[mi] = *(const bf16x8*)&As[(wm * 64 + mi * 16 + lo) * 64 +
                                         (((ks * 4 + hi) ^ key) * 8)];
#pragma unroll
        for (int mi = 0; mi < 4; ++mi)
#pragma unroll
            for (int ni = 0; ni < 4; ++ni)
                acc[mi][ni] = __builtin_amdgcn_mfma_f32_16x16x32_bf16(
                    af[mi], bfr[ks][ni], acc[mi][ni], 0, 0, 0);
    }

    const int col0 = nbase + wn * 64 + lo;
    const long long row00 = rbase + wm * 64 + hi * 4;
#pragma unroll
    for (int ni = 0; ni < 4; ++ni) {
        int col = col0 + ni * 16;
        float bv = bias[col];
#pragma unroll
        for (int mi = 0; mi < 4; ++mi) {
            long long r0 = row00 + mi * 16;
#pragma unroll
            for (int r = 0; r < 4; ++r) {
                float v = fmaxf(acc[mi][ni][r] + bv, 0.f);   // ReLU
                C[(r0 + r) * NH + col] = __float2bfloat16(v);
            }
        }
    }
}

// ---------------------------------------------------------------------------
// GEMM2 (K=512): counted-vmcnt 2-deep pipeline (R13 proven: 58 us, 0 conflicts).
__global__ __launch_bounds__(256) void gemm2_db(const __hip_bfloat16* __restrict__ A,
                                                const __hip_bfloat16* __restrict__ BT,
                                                const float* __restrict__ bias,
                                                __hip_bfloat16* __restrict__ C,
                                                float* __restrict__ partial) {
    constexpr int BK = 64;
    __shared__ __align__(16) char smem[65536];   // 2 sets x (A 16KB | B 16KB)
    float* smsum = (float*)smem;                 // alias set0 (dead after loop)
    float* smsq  = (float*)(smem + 2048);

    const int orig = blockIdx.x;
    const int L = (orig & 7) * CPX + (orig >> 3);
    const int mb = L >> 2, nb = L & 3;

    const int tid = threadIdx.x;
    const int lane = tid & 63;
    const int w = tid >> 6;
    const int wm = w >> 1, wn = w & 1;
    const long long rbase = (long long)mb * 128;
    const int nbase = nb * 128;
    const int r8  = lane >> 3;            // stage row within 8-row group
    const int swc = (lane & 7) ^ r8;      // pre-swizzled global chunk (rule #21)
    const int key = lane & 7;             // read-side swizzle key
    const int lo = lane & 15, hi = lane >> 4;

    const __hip_bfloat16* gaBase =
        A + (rbase + w * 32 + r8) * (long long)NH + swc * 8;
    const __hip_bfloat16* gbBase =
        BT + (long long)(nbase + w * 32 + r8) * NH + swc * 8;
    const int laOff = (w * 32) * BK;

    auto STAGE = [&](int s, int kb) {
        __hip_bfloat16* la = (__hip_bfloat16*)(smem + s * 32768) + laOff;
        __hip_bfloat16* lb = (__hip_bfloat16*)(smem + s * 32768 + 16384) + laOff;
#pragma unroll
        for (int t = 0; t < 4; ++t)
            GLOAD16(gaBase + kb + (long long)t * 8 * NH, la + t * 8 * BK);
#pragma unroll
        for (int t = 0; t < 4; ++t)
            GLOAD16(gbBase + kb + (long long)t * 8 * NH, lb + t * 8 * BK);
    };

    f32x4 acc[4][4];
#pragma unroll
    for (int i = 0; i < 4; ++i)
#pragma unroll
        for (int j = 0; j < 4; ++j) acc[i][j] = (f32x4){0.f, 0.f, 0.f, 0.f};

    // prologue: 2-deep prefetch (16 loads outstanding per wave)
    STAGE(0, 0);
    STAGE(1, BK);

#pragma unroll
    for (int t = 0; t < 8; ++t) {
        if (t == 7) { asm volatile("s_waitcnt vmcnt(0)" ::: "memory"); }
        else        { asm volatile("s_waitcnt vmcnt(8)" ::: "memory"); }
        __builtin_amdgcn_s_barrier();          // all waves' DMA for cur landed
        __builtin_amdgcn_sched_barrier(0);

        const __hip_bfloat16* Ac = (const __hip_bfloat16*)(smem + (t & 1) * 32768);
        const __hip_bfloat16* Bc = Ac + 8192;  // +16384 bytes
#pragma unroll
        for (int ks = 0; ks < 2; ++ks) {
            bf16x8 af[4], bfr[4];
#pragma unroll
            for (int mi = 0; mi < 4; ++mi)
                af[mi] = *(const bf16x8*)&Ac[(wm * 64 + mi * 16 + lo) * BK +
                                             (((ks * 4 + hi) ^ key) * 8)];
#pragma unroll
            for (int ni = 0; ni < 4; ++ni)
                bfr[ni] = *(const bf16x8*)&Bc[(wn * 64 + ni * 16 + lo) * BK +
                                              (((ks * 4 + hi) ^ key) * 8)];
#pragma unroll
            for (int mi = 0; mi < 4; ++mi)
#pragma unroll
                for (int ni = 0; ni < 4; ++ni)
                    acc[mi][ni] = __builtin_amdgcn_mfma_f32_16x16x32_bf16(
                        af[mi], bfr[ni], acc[mi][ni], 0, 0, 0);
        }
        __builtin_amdgcn_sched_barrier(0);
        __builtin_amdgcn_s_barrier();          // all waves done reading cur
        __builtin_amdgcn_sched_barrier(0);
        if (t < 6) STAGE(t & 1, (t + 2) * BK); // refill freed buffer, 2 ahead
    }

    // epilogue: vmcnt==0 here; full barrier before LDS alias reuse
    __syncthreads();
    if (tid < 128) { smsum[tid] = 0.f; smsq[tid] = 0.f; }
    __syncthreads();
    const int col0 = nbase + wn * 64 + lo;
    const long long row00 = rbase + wm * 64 + hi * 4;
#pragma unroll
    for (int ni = 0; ni < 4; ++ni) {
        int col = col0 + ni * 16;
        float bv = bias[col];
        float s = 0.f, q = 0.f;
#pragma unroll
        for (int mi = 0; mi < 4; ++mi) {
            long long r0 = row00 + mi * 16;
#pragma unroll
            for (int r = 0; r < 4; ++r) {
                float v = acc[mi][ni][r] + bv;
                C[(r0 + r) * NH + col] = __float2bfloat16(v);
                if ((r0 + r) < NN) { s += v; q += v * v; }
            }
        }
        s += __shfl_xor(s, 16); s += __shfl_xor(s, 32);
        q += __shfl_xor(q, 16); q += __shfl_xor(q, 32);
        if (lane < 16) {
            atomicAdd(&smsum[wn * 64 + ni * 16 + lane], s);
            atomicAdd(&smsq[wn * 64 + ni * 16 + lane], q);
        }
    }
    __syncthreads();
    if (tid < 128) {
        partial[mb * 1024 + nbase + tid] = smsum[tid];
        partial[mb * 1024 + 512 + nbase + tid] = smsq[tid];
    }
}

// reduce per-block partials: stats[j] = sum_mb partial[mb*1024 + j], j<1024
__global__ __launch_bounds__(256) void stats_reduce(const float* __restrict__ partial,
                                                    float* __restrict__ stats) {
    int j = blockIdx.x * 256 + threadIdx.x;   // 0..1023
    float s = 0.f;
    for (int mb = 0; mb < MB; ++mb) s += partial[mb * 1024 + j];
    stats[j] = s;
}

// BN(train stats) + ReLU + classifier fused; bf16 h2, per-lane register params
__global__ __launch_bounds__(256) void bn_cls(const __hip_bfloat16* __restrict__ h2b,
                                              const float* __restrict__ stats,
                                              const float* __restrict__ gamma,
                                              const float* __restrict__ beta,
                                              const float* __restrict__ Wc,
                                              const float* __restrict__ bc,
                                              float* __restrict__ out) {
    int tid = threadIdx.x;
    int lane = tid & 63;
    int k0 = lane * 8;
    float sc[8], sh[8], w0[8], w1[8];
#pragma unroll
    for (int j = 0; j < 8; ++j) {
        int k = k0 + j;
        float mean = stats[k] * (1.0f / NN);
        float var = stats[512 + k] * (1.0f / NN) - mean * mean;
        float rs = rsqrtf(var + 1e-5f);
        float s = gamma[k] * rs;
        sc[j] = s;
        sh[j] = beta[k] - mean * s;
        w0[j] = Wc[2 * k];
        w1[j] = Wc[2 * k + 1];
    }
    float bc0 = bc[0], bc1 = bc[1];
    int wid = blockIdx.x * 4 + (tid >> 6);
    int nw = gridDim.x * 4;
    for (int row = wid; row < NN; row += nw) {
        bf16x8 v8 = *(const bf16x8*)&h2b[(long long)row * NH + k0];
        float a0 = 0.f, a1 = 0.f;
#pragma unroll
        for (int j = 0; j < 8; ++j) {
            float v = __bfloat162float(((const __hip_bfloat16*)&v8)[j]);
            float hn = fmaxf(fmaf(v, sc[j], sh[j]), 0.f);
            a0 = fmaf(hn, w0[j], a0);
            a1 = fmaf(hn, w1[j], a1);
        }
#pragma unroll
        for (int off = 32; off; off >>= 1) {
            a0 += __shfl_xor(a0, off);
            a1 += __shfl_xor(a1, off);
        }
        if (lane == 0) {
            out[(long long)row * 2 + 0] = a0 + bc0;
            out[(long long)row * 2 + 1] = a1 + bc1;
        }
    }
}

// ---------------------------------------------------------------------------
extern "C" void kernel_launch(void* const* d_in, const int* in_sizes, int n_in,
                              void* d_out, int out_size, void* d_ws, size_t ws_size,
                              hipStream_t stream) {
    const float* x     = (const float*)d_in[0];
    const void*  ei    = d_in[1];
    const float* W1    = (const float*)d_in[2];
    const float* b1    = (const float*)d_in[3];
    const float* W2    = (const float*)d_in[4];
    const float* b2    = (const float*)d_in[5];
    const float* gamma = (const float*)d_in[6];
    const float* beta  = (const float*)d_in[7];
    const float* Wc    = (const float*)d_in[8];
    const float* bc    = (const float*)d_in[9];
    float* out = (float*)d_out;

    // workspace carve-up (256B aligned)
    char* base = (char*)d_ws;
    size_t o = 0;
    auto alloc = [&](size_t bytes) {
        char* p = base + o;
        o = (o + bytes + 255) & ~(size_t)255;
        return p;
    };
    __hip_bfloat16* h0b     = (__hip_bfloat16*)alloc((size_t)MP * NF * 2);
    __hip_bfloat16* h1b     = (__hip_bfloat16*)alloc((size_t)MP * NH * 2);
    __hip_bfloat16* h2b     = (__hip_bfloat16*)alloc((size_t)MP * NH * 2);
    __hip_bfloat16* xb      = (__hip_bfloat16*)alloc((size_t)NN * NF * 2);
    __hip_bfloat16* w1t     = (__hip_bfloat16*)alloc((size_t)NH * NF * 2);
    __hip_bfloat16* w2t     = (__hip_bfloat16*)alloc((size_t)NH * NH * 2);
    int*            ebP     = (int*)alloc((size_t)NBK * EBCAP * 4);
    int*            bcnt    = (int*)alloc(256 * 4);
    int*            bbase   = (int*)alloc(256 * 4);
    int*            rowptr  = (int*)alloc((size_t)(NN + 1) * 4);
    int*            csr     = (int*)alloc((size_t)NE * 4);
    float*          partial = (float*)alloc((size_t)MB * 1024 * 4);
    float*          stats   = (float*)alloc(1024 * 4);
    int*            flag    = (int*)alloc(256);

    hipMemsetAsync(bcnt, 0, NBK * 4, stream);
    detect_idx<<<1, 1, 0, stream>>>((const int*)ei, flag);

    // CSR build via 2-pass LDS bucket sort (no scattered global atomics)
    bucketA<<<ABLK, 256, 0, stream>>>(ei, flag, bcnt, ebP);
    scan_bsum<<<1, 256, 0, stream>>>(bcnt, bbase);
    bucketB<<<NBK, 256, 0, stream>>>(ebP, bcnt, bbase, rowptr, csr);

    cvt_all<<<XBLK + W1BLK + W2BLK, 256, 0, stream>>>(x, W1, W2, xb, w1t, w2t);
    gather<<<MP / 4, 256, 0, stream>>>(xb, rowptr, csr, h0b);

    gemm1_staged<<<GRID, 256, 0, stream>>>(h0b, w1t, b1, h1b);
    gemm2_db<<<GRID, 256, 0, stream>>>(h1b, w2t, b2, h2b, partial);

    stats_reduce<<<4, 256, 0, stream>>>(partial, stats);
    bn_cls<<<512, 256, 0, stream>>>(h2b, stats, gamma, beta, Wc, bc, out);
}

// Round 16
// 165.931 us; speedup vs baseline: 1.5694x; 1.0086x over previous
//
#include <hip/hip_runtime.h>
#include <hip/hip_bf16.h>

#define NN 50000      // nodes
#define MP 50176      // padded nodes (392 * 128)
#define NF 64         // features
#define NH 512        // hidden
#define NE 800000     // edges
#define NBK 196       // dst buckets (dst >> 8)
#define EBCAP 8192    // per-bucket capacity (2x Poisson mean 4082, sd 64)
#define ABLK 391      // bucketA blocks (x 2048 edges)
#define MB 392        // M blocks = MP/128
#define GRID (MB * 4) // 1568 = 8 * 196
#define CPX (GRID / 8)

typedef __attribute__((ext_vector_type(8))) short bf16x8;
typedef __attribute__((ext_vector_type(4))) float f32x4;

#define GLOAD16(g, l)                                                        \
    __builtin_amdgcn_global_load_lds(                                        \
        (const __attribute__((address_space(1))) unsigned int*)(g),          \
        (__attribute__((address_space(3))) unsigned int*)(l), 16, 0, 0)

__device__ __forceinline__ float bfu(unsigned short u) {
    union { float f; unsigned int i; } c;
    c.i = ((unsigned int)u) << 16;
    return c.f;
}

// ---------------------------------------------------------------------------
// detect whether edge_index is int64 (high dwords all zero) or int32
__global__ void detect_idx(const int* __restrict__ ei, int* __restrict__ flag) {
    if (threadIdx.x == 0 && blockIdx.x == 0) {
        int any = 0;
        for (int i = 0; i < 32; ++i) any |= ei[2 * i + 1];
        *flag = (any == 0) ? 1 : 0;   // 1 => int64 layout
    }
}

// ---------------------------------------------------------------------------
// Bucket sort pass A: partition edges into 196 dst-buckets (dst>>8).
// Payload packed into one int: (dst&255)<<16 | src  (src < 50000 < 2^16).
__global__ __launch_bounds__(256) void bucketA(const void* __restrict__ eiv,
                                               const int* __restrict__ flag,
                                               int* __restrict__ bcnt,
                                               int* __restrict__ ebP) {
    __shared__ int hist[NBK];
    __shared__ int lcur[NBK];
    const int tid = threadIdx.x;
    const int chunk = blockIdx.x * 2048;
    const int lim = min(2048, NE - chunk);
    const bool is64 = (*flag != 0);
    const long long* ei64 = (const long long*)eiv;
    const int* ei32 = (const int*)eiv;

    for (int i = tid; i < NBK; i += 256) hist[i] = 0;
    __syncthreads();
    for (int i = tid; i < lim; i += 256) {
        int d = is64 ? (int)ei64[NE + chunk + i] : ei32[NE + chunk + i];
        atomicAdd(&hist[d >> 8], 1);
    }
    __syncthreads();
    for (int i = tid; i < NBK; i += 256) {
        int c = hist[i];
        lcur[i] = c ? atomicAdd(&bcnt[i], c) : 0;   // reserve run in bucket i
    }
    __syncthreads();
    for (int i = tid; i < lim; i += 256) {
        int s, d;
        if (is64) { s = (int)ei64[chunk + i]; d = (int)ei64[NE + chunk + i]; }
        else      { s = ei32[chunk + i];      d = ei32[NE + chunk + i]; }
        int b = d >> 8;
        int p = atomicAdd(&lcur[b], 1);             // LDS cursor -> global slot
        ebP[b * EBCAP + p] = ((d & 255) << 16) | s;
    }
}

// exclusive scan of the NBK bucket counts (1 block) -> bucket bases
__global__ __launch_bounds__(256) void scan_bsum(const int* __restrict__ bsum,
                                                 int* __restrict__ boff) {
    __shared__ int sm[256];
    int tid = threadIdx.x;
    int v = (tid < NBK) ? bsum[tid] : 0;
    sm[tid] = v;
    __syncthreads();
    int acc = v;
#pragma unroll
    for (int off = 1; off < 256; off <<= 1) {
        int t = (tid >= off) ? sm[tid - off] : 0;
        __syncthreads();
        acc += t;
        sm[tid] = acc;
        __syncthreads();
    }
    if (tid < NBK) boff[tid] = acc - v;         // exclusive
}

// Bucket sort pass B: one block per bucket; LDS counting sort -> rowptr, csr.
__global__ __launch_bounds__(256) void bucketB(const int* __restrict__ ebP,
                                               const int* __restrict__ bcnt,
                                               const int* __restrict__ bbase,
                                               int* __restrict__ rowptr,
                                               int* __restrict__ csr) {
    __shared__ int hist[256], sm[256], curs[256];
    const int b = blockIdx.x;
    const int tid = threadIdx.x;
    const int n0 = b << 8;
    const int cnt = bcnt[b];
    const int base = bbase[b];

    hist[tid] = 0;
    __syncthreads();
    for (int i = tid; i < cnt; i += 256)
        atomicAdd(&hist[(ebP[b * EBCAP + i] >> 16) & 255], 1);
    __syncthreads();
    int v = hist[tid];
    sm[tid] = v;
    __syncthreads();
    int acc = v;
#pragma unroll
    for (int off = 1; off < 256; off <<= 1) {
        int t = (tid >= off) ? sm[tid - off] : 0;
        __syncthreads();
        acc += t;
        sm[tid] = acc;
        __syncthreads();
    }
    int excl = acc - v;
    if (n0 + tid < NN) rowptr[n0 + tid] = base + excl;   // coalesced
    curs[tid] = excl;
    __syncthreads();
    for (int i = tid; i < cnt; i += 256) {
        int p = ebP[b * EBCAP + i];
        int lp = atomicAdd(&curs[(p >> 16) & 255], 1);   // LDS cursor
        csr[base + lp] = p & 0xFFFF;
    }
    if (b == 0 && tid == 0) rowptr[NN] = NE;
}

// one launch for all fp32->bf16 conversions: x, W1^T, W2^T
#define XBLK  (NN * NF / 4 / 256)        // 3125
#define W1BLK (NF * NH / 256)            // 128
#define W2BLK (NH * NH / 256)            // 1024
__global__ __launch_bounds__(256) void cvt_all(const float* __restrict__ x,
                                               const float* __restrict__ W1,
                                               const float* __restrict__ W2,
                                               __hip_bfloat16* __restrict__ xb,
                                               __hip_bfloat16* __restrict__ w1t,
                                               __hip_bfloat16* __restrict__ w2t) {
    int bb = blockIdx.x;
    if (bb < XBLK) {
        int t = bb * 256 + threadIdx.x;
        float4 v = *(const float4*)&x[t * 4];
        union { ushort4 u; __hip_bfloat16 h[4]; } o;
        o.h[0] = __float2bfloat16(v.x);
        o.h[1] = __float2bfloat16(v.y);
        o.h[2] = __float2bfloat16(v.z);
        o.h[3] = __float2bfloat16(v.w);
        *(ushort4*)&xb[t * 4] = o.u;
    } else if (bb < XBLK + W1BLK) {
        int t = (bb - XBLK) * 256 + threadIdx.x;   // over NF*NH
        int n = t % NH, k = t / NH;
        w1t[n * NF + k] = __float2bfloat16(W1[t]);
    } else {
        int t = (bb - XBLK - W1BLK) * 256 + threadIdx.x;   // over NH*NH
        int n = t % NH, k = t / NH;
        w2t[n * NH + k] = __float2bfloat16(W2[t]);
    }
}

// gather-sum, one WAVE per node, 4 neighbor rows in flight per iteration.
// lane = (slot-group g = lane>>4) x (feature-quad f4 = lane&15); each lane
// loads 8B (4 bf16 features) -> 16 lanes cover a 128B row, groups g=0..3
// handle slots e+g. Cross-group reduce = 2 shfl_xor (sum is commutative).
__global__ __launch_bounds__(256) void gather(const __hip_bfloat16* __restrict__ xb,
                                              const int* __restrict__ rowptr,
                                              const int* __restrict__ csr,
                                              __hip_bfloat16* __restrict__ h0b) {
    int n = blockIdx.x * 4 + (threadIdx.x >> 6);   // node id
    int lane = threadIdx.x & 63;
    int g = lane >> 4;
    int f4 = (lane & 15) * 4;
    if (n >= MP) return;
    if (n >= NN) {
        if (g == 0)
            *(ushort4*)&h0b[(long long)n * NF + f4] = make_ushort4(0, 0, 0, 0);
        return;
    }
    float a0 = 0.f, a1 = 0.f, a2 = 0.f, a3 = 0.f;
    if (g == 0) {   // self term
        ushort4 v = *(const ushort4*)&xb[(long long)n * NF + f4];
        a0 = bfu(v.x); a1 = bfu(v.y); a2 = bfu(v.z); a3 = bfu(v.w);
    }
    int e0 = rowptr[n], e1 = rowptr[n + 1];
    for (int e = e0 + g; e < e1; e += 4) {
        int s = csr[e];                               // broadcast within group
        ushort4 v = *(const ushort4*)&xb[(long long)s * NF + f4];
        a0 += bfu(v.x); a1 += bfu(v.y); a2 += bfu(v.z); a3 += bfu(v.w);
    }
    a0 += __shfl_xor(a0, 16); a0 += __shfl_xor(a0, 32);
    a1 += __shfl_xor(a1, 16); a1 += __shfl_xor(a1, 32);
    a2 += __shfl_xor(a2, 16); a2 += __shfl_xor(a2, 32);
    a3 += __shfl_xor(a3, 16); a3 += __shfl_xor(a3, 32);
    if (g == 0) {
        union { ushort4 u; __hip_bfloat16 h[4]; } o;
        o.h[0] = __float2bfloat16(a0);
        o.h[1] = __float2bfloat16(a1);
        o.h[2] = __float2bfloat16(a2);
        o.h[3] = __float2bfloat16(a3);
        *(ushort4*)&h0b[(long long)n * NF + f4] = o.u;
    }
}

// ---------------------------------------------------------------------------
// GEMM1 (K=64): A staged via global_load_lds (issued first), B fragments read
// direct from L1-hot w1t while the DMA is in flight; single barrier.
__global__ __launch_bounds__(256) void gemm1_staged(const __hip_bfloat16* __restrict__ A,
                                                    const __hip_bfloat16* __restrict__ BT,
                                                    const float* __restrict__ bias,
                                                    __hip_bfloat16* __restrict__ C) {
    __shared__ __hip_bfloat16 As[128 * 64];   // 16 KB
    const int orig = blockIdx.x;
    const int L = (orig & 7) * CPX + (orig >> 3);
    const int mb = L >> 2, nb = L & 3;

    const int tid = threadIdx.x;
    const int lane = tid & 63;
    const int w = tid >> 6;
    const int wm = w >> 1, wn = w & 1;
    const long long rbase = (long long)mb * 128;
    const int nbase = nb * 128;
    const int r8  = lane >> 3;
    const int swc = (lane & 7) ^ r8;      // pre-swizzled global chunk (rule #21)
    const int key = lane & 7;
    const int lo = lane & 15, hi = lane >> 4;

    // issue A-tile DMA first
    {
        const __hip_bfloat16* ga = A + (rbase + w * 32 + r8) * NF + swc * 8;
        __hip_bfloat16* la = As + (w * 32) * 64;
#pragma unroll
        for (int t = 0; t < 4; ++t)
            GLOAD16(ga + t * 8 * NF, la + t * 8 * 64);
    }
    // B fragments direct from global (w1t 64 KB, L1/L2-hot) — hides DMA latency
    bf16x8 bfr[2][4];
#pragma unroll
    for (int ks = 0; ks < 2; ++ks)
#pragma unroll
        for (int ni = 0; ni < 4; ++ni)
            bfr[ks][ni] = *(const bf16x8*)&BT[(nbase + wn * 64 + ni * 16 + lo) * NF +
                                             ks * 32 + hi * 8];
    __syncthreads();   // A landed

    f32x4 acc[4][4];
#pragma unroll
    for (int i = 0; i < 4; ++i)
#pragma unroll
        for (int j = 0; j < 4; ++j) acc[i][j] = (f32x4){0.f, 0.f, 0.f, 0.f};

#pragma unroll
    for (int ks = 0; ks < 2; ++ks) {
        bf16x8 af[4];
#pragma unroll
        for (int mi = 0; mi < 4; ++mi)
            af[mi] = *(const bf16x8*)&As[(wm * 64 + mi * 16 + lo) * 64 +
                                         (((ks * 4 + hi) ^ key) * 8)];
#pragma unroll
        for (int mi = 0; mi < 4; ++mi)
#pragma unroll
            for (int ni = 0; ni < 4; ++ni)
                acc[mi][ni] = __builtin_amdgcn_mfma_f32_16x16x32_bf16(
                    af[mi], bfr[ks][ni], acc[mi][ni], 0, 0, 0);
    }

    const int col0 = nbase + wn * 64 + lo;
    const long long row00 = rbase + wm * 64 + hi * 4;
#pragma unroll
    for (int ni = 0; ni < 4; ++ni) {
        int col = col0 + ni * 16;
        float bv = bias[col];
#pragma unroll
        for (int mi = 0; mi < 4; ++mi) {
            long long r0 = row00 + mi * 16;
#pragma unroll
            for (int r = 0; r < 4; ++r) {
                float v = fmaxf(acc[mi][ni][r] + bv, 0.f);   // ReLU
                C[(r0 + r) * NH + col] = __float2bfloat16(v);
            }
        }
    }
}

// ---------------------------------------------------------------------------
// GEMM2 (K=512): counted-vmcnt 2-deep pipeline (R13 proven) + T5 setprio
// around the MFMA cluster (pre-committed: null per m190 is acceptable).
__global__ __launch_bounds__(256) void gemm2_db(const __hip_bfloat16* __restrict__ A,
                                                const __hip_bfloat16* __restrict__ BT,
                                                const float* __restrict__ bias,
                                                __hip_bfloat16* __restrict__ C,
                                                float* __restrict__ partial) {
    constexpr int BK = 64;
    __shared__ __align__(16) char smem[65536];   // 2 sets x (A 16KB | B 16KB)
    float* smsum = (float*)smem;                 // alias set0 (dead after loop)
    float* smsq  = (float*)(smem + 2048);

    const int orig = blockIdx.x;
    const int L = (orig & 7) * CPX + (orig >> 3);
    const int mb = L >> 2, nb = L & 3;

    const int tid = threadIdx.x;
    const int lane = tid & 63;
    const int w = tid >> 6;
    const int wm = w >> 1, wn = w & 1;
    const long long rbase = (long long)mb * 128;
    const int nbase = nb * 128;
    const int r8  = lane >> 3;            // stage row within 8-row group
    const int swc = (lane & 7) ^ r8;      // pre-swizzled global chunk (rule #21)
    const int key = lane & 7;             // read-side swizzle key
    const int lo = lane & 15, hi = lane >> 4;

    const __hip_bfloat16* gaBase =
        A + (rbase + w * 32 + r8) * (long long)NH + swc * 8;
    const __hip_bfloat16* gbBase =
        BT + (long long)(nbase + w * 32 + r8) * NH + swc * 8;
    const int laOff = (w * 32) * BK;

    auto STAGE = [&](int s, int kb) {
        __hip_bfloat16* la = (__hip_bfloat16*)(smem + s * 32768) + laOff;
        __hip_bfloat16* lb = (__hip_bfloat16*)(smem + s * 32768 + 16384) + laOff;
#pragma unroll
        for (int t = 0; t < 4; ++t)
            GLOAD16(gaBase + kb + (long long)t * 8 * NH, la + t * 8 * BK);
#pragma unroll
        for (int t = 0; t < 4; ++t)
            GLOAD16(gbBase + kb + (long long)t * 8 * NH, lb + t * 8 * BK);
    };

    f32x4 acc[4][4];
#pragma unroll
    for (int i = 0; i < 4; ++i)
#pragma unroll
        for (int j = 0; j < 4; ++j) acc[i][j] = (f32x4){0.f, 0.f, 0.f, 0.f};

    // prologue: 2-deep prefetch (16 loads outstanding per wave)
    STAGE(0, 0);
    STAGE(1, BK);

#pragma unroll
    for (int t = 0; t < 8; ++t) {
        if (t == 7) { asm volatile("s_waitcnt vmcnt(0)" ::: "memory"); }
        else        { asm volatile("s_waitcnt vmcnt(8)" ::: "memory"); }
        __builtin_amdgcn_s_barrier();          // all waves' DMA for cur landed
        __builtin_amdgcn_sched_barrier(0);

        const __hip_bfloat16* Ac = (const __hip_bfloat16*)(smem + (t & 1) * 32768);
        const __hip_bfloat16* Bc = Ac + 8192;  // +16384 bytes
        __builtin_amdgcn_s_setprio(1);
#pragma unroll
        for (int ks = 0; ks < 2; ++ks) {
            bf16x8 af[4], bfr[4];
#pragma unroll
            for (int mi = 0; mi < 4; ++mi)
                af[mi] = *(const bf16x8*)&Ac[(wm * 64 + mi * 16 + lo) * BK +
                                             (((ks * 4 + hi) ^ key) * 8)];
#pragma unroll
            for (int ni = 0; ni < 4; ++ni)
                bfr[ni] = *(const bf16x8*)&Bc[(wn * 64 + ni * 16 + lo) * BK +
                                              (((ks * 4 + hi) ^ key) * 8)];
#pragma unroll
            for (int mi = 0; mi < 4; ++mi)
#pragma unroll
                for (int ni = 0; ni < 4; ++ni)
                    acc[mi][ni] = __builtin_amdgcn_mfma_f32_16x16x32_bf16(
                        af[mi], bfr[ni], acc[mi][ni], 0, 0, 0);
        }
        __builtin_amdgcn_s_setprio(0);
        __builtin_amdgcn_sched_barrier(0);
        __builtin_amdgcn_s_barrier();          // all waves done reading cur
        __builtin_amdgcn_sched_barrier(0);
        if (t < 6) STAGE(t & 1, (t + 2) * BK); // refill freed buffer, 2 ahead
    }

    // epilogue: vmcnt==0 here; full barrier before LDS alias reuse
    __syncthreads();
    if (tid < 128) { smsum[tid] = 0.f; smsq[tid] = 0.f; }
    __syncthreads();
    const int col0 = nbase + wn * 64 + lo;
    const long long row00 = rbase + wm * 64 + hi * 4;
#pragma unroll
    for (int ni = 0; ni < 4; ++ni) {
        int col = col0 + ni * 16;
        float bv = bias[col];
        float s = 0.f, q = 0.f;
#pragma unroll
        for (int mi = 0; mi < 4; ++mi) {
            long long r0 = row00 + mi * 16;
#pragma unroll
            for (int r = 0; r < 4; ++r) {
                float v = acc[mi][ni][r] + bv;
                C[(r0 + r) * NH + col] = __float2bfloat16(v);
                if ((r0 + r) < NN) { s += v; q += v * v; }
            }
        }
        s += __shfl_xor(s, 16); s += __shfl_xor(s, 32);
        q += __shfl_xor(q, 16); q += __shfl_xor(q, 32);
        if (lane < 16) {
            atomicAdd(&smsum[wn * 64 + ni * 16 + lane], s);
            atomicAdd(&smsq[wn * 64 + ni * 16 + lane], q);
        }
    }
    __syncthreads();
    if (tid < 128) {
        partial[mb * 1024 + nbase + tid] = smsum[tid];
        partial[mb * 1024 + 512 + nbase + tid] = smsq[tid];
    }
}

// reduce per-block partials: stats[j] = sum_mb partial[mb*1024 + j], j<1024
__global__ __launch_bounds__(256) void stats_reduce(const float* __restrict__ partial,
                                                    float* __restrict__ stats) {
    int j = blockIdx.x * 256 + threadIdx.x;   // 0..1023
    float s = 0.f;
    for (int mb = 0; mb < MB; ++mb) s += partial[mb * 1024 + j];
    stats[j] = s;
}

// BN(train stats) + ReLU + classifier fused; bf16 h2, per-lane register params
__global__ __launch_bounds__(256) void bn_cls(const __hip_bfloat16* __restrict__ h2b,
                                              const float* __restrict__ stats,
                                              const float* __restrict__ gamma,
                                              const float* __restrict__ beta,
                                              const float* __restrict__ Wc,
                                              const float* __restrict__ bc,
                                              float* __restrict__ out) {
    int tid = threadIdx.x;
    int lane = tid & 63;
    int k0 = lane * 8;
    float sc[8], sh[8], w0[8], w1[8];
#pragma unroll
    for (int j = 0; j < 8; ++j) {
        int k = k0 + j;
        float mean = stats[k] * (1.0f / NN);
        float var = stats[512 + k] * (1.0f / NN) - mean * mean;
        float rs = rsqrtf(var + 1e-5f);
        float s = gamma[k] * rs;
        sc[j] = s;
        sh[j] = beta[k] - mean * s;
        w0[j] = Wc[2 * k];
        w1[j] = Wc[2 * k + 1];
    }
    float bc0 = bc[0], bc1 = bc[1];
    int wid = blockIdx.x * 4 + (tid >> 6);
    int nw = gridDim.x * 4;
    for (int row = wid; row < NN; row += nw) {
        bf16x8 v8 = *(const bf16x8*)&h2b[(long long)row * NH + k0];
        float a0 = 0.f, a1 = 0.f;
#pragma unroll
        for (int j = 0; j < 8; ++j) {
            float v = __bfloat162float(((const __hip_bfloat16*)&v8)[j]);
            float hn = fmaxf(fmaf(v, sc[j], sh[j]), 0.f);
            a0 = fmaf(hn, w0[j], a0);
            a1 = fmaf(hn, w1[j], a1);
        }
#pragma unroll
        for (int off = 32; off; off >>= 1) {
            a0 += __shfl_xor(a0, off);
            a1 += __shfl_xor(a1, off);
        }
        if (lane == 0) {
            out[(long long)row * 2 + 0] = a0 + bc0;
            out[(long long)row * 2 + 1] = a1 + bc1;
        }
    }
}

// ---------------------------------------------------------------------------
extern "C" void kernel_launch(void* const* d_in, const int* in_sizes, int n_in,
                              void* d_out, int out_size, void* d_ws, size_t ws_size,
                              hipStream_t stream) {
    const float* x     = (const float*)d_in[0];
    const void*  ei    = d_in[1];
    const float* W1    = (const float*)d_in[2];
    const float* b1    = (const float*)d_in[3];
    const float* W2    = (const float*)d_in[4];
    const float* b2    = (const float*)d_in[5];
    const float* gamma = (const float*)d_in[6];
    const float* beta  = (const float*)d_in[7];
    const float* Wc    = (const float*)d_in[8];
    const float* bc    = (const float*)d_in[9];
    float* out = (float*)d_out;

    // workspace carve-up (256B aligned)
    char* base = (char*)d_ws;
    size_t o = 0;
    auto alloc = [&](size_t bytes) {
        char* p = base + o;
        o = (o + bytes + 255) & ~(size_t)255;
        return p;
    };
    __hip_bfloat16* h0b     = (__hip_bfloat16*)alloc((size_t)MP * NF * 2);
    __hip_bfloat16* h1b     = (__hip_bfloat16*)alloc((size_t)MP * NH * 2);
    __hip_bfloat16* h2b     = (__hip_bfloat16*)alloc((size_t)MP * NH * 2);
    __hip_bfloat16* xb      = (__hip_bfloat16*)alloc((size_t)NN * NF * 2);
    __hip_bfloat16* w1t     = (__hip_bfloat16*)alloc((size_t)NH * NF * 2);
    __hip_bfloat16* w2t     = (__hip_bfloat16*)alloc((size_t)NH * NH * 2);
    int*            ebP     = (int*)alloc((size_t)NBK * EBCAP * 4);
    int*            bcnt    = (int*)alloc(256 * 4);
    int*            bbase   = (int*)alloc(256 * 4);
    int*            rowptr  = (int*)alloc((size_t)(NN + 1) * 4);
    int*            csr     = (int*)alloc((size_t)NE * 4);
    float*          partial = (float*)alloc((size_t)MB * 1024 * 4);
    float*          stats   = (float*)alloc(1024 * 4);
    int*            flag    = (int*)alloc(256);

    hipMemsetAsync(bcnt, 0, NBK * 4, stream);
    detect_idx<<<1, 1, 0, stream>>>((const int*)ei, flag);

    // CSR build via 2-pass LDS bucket sort (no scattered global atomics)
    bucketA<<<ABLK, 256, 0, stream>>>(ei, flag, bcnt, ebP);
    scan_bsum<<<1, 256, 0, stream>>>(bcnt, bbase);
    bucketB<<<NBK, 256, 0, stream>>>(ebP, bcnt, bbase, rowptr, csr);

    cvt_all<<<XBLK + W1BLK + W2BLK, 256, 0, stream>>>(x, W1, W2, xb, w1t, w2t);
    gather<<<MP / 4, 256, 0, stream>>>(xb, rowptr, csr, h0b);

    gemm1_staged<<<GRID, 256, 0, stream>>>(h0b, w1t, b1, h1b);
    gemm2_db<<<GRID, 256, 0, stream>>>(h1b, w2t, b2, h2b, partial);

    stats_reduce<<<4, 256, 0, stream>>>(partial, stats);
    bn_cls<<<512, 256, 0, stream>>>(h2b, stats, gamma, beta, Wc, bc, out);
}